// Round 1
// baseline (610.064 us; speedup 1.0000x reference)
//
#include <hip/hip_runtime.h>
#include <cstdint>
#include <cstddef>

typedef unsigned short u16;
typedef float floatx4 __attribute__((ext_vector_type(4)));
typedef __bf16 bf16x8 __attribute__((ext_vector_type(8)));
typedef unsigned short u16x8 __attribute__((ext_vector_type(8)));
typedef unsigned short u16x4 __attribute__((ext_vector_type(4)));

// ---------- helpers ----------
__device__ __forceinline__ u16 f2bf(float f) {
  unsigned u = __float_as_uint(f);
  unsigned r = u + 0x7FFFu + ((u >> 16) & 1u);   // RNE
  return (u16)(r >> 16);
}
__device__ __forceinline__ float bf2f(u16 h) {
  return __uint_as_float(((unsigned)h) << 16);
}
__device__ __forceinline__ void gl_lds16(const void* g, void* l) {
  __builtin_amdgcn_global_load_lds(
      (const __attribute__((address_space(1))) unsigned int*)g,
      (__attribute__((address_space(3))) unsigned int*)l, 16, 0, 0);
}
__device__ __forceinline__ float wsum(float v) {
#pragma unroll
  for (int m = 32; m > 0; m >>= 1) v += __shfl_xor(v, m, 64);
  return v;
}
__device__ __forceinline__ float wmaxr(float v) {
#pragma unroll
  for (int m = 32; m > 0; m >>= 1) v = fmaxf(v, __shfl_xor(v, m, 64));
  return v;
}
template <int NW>
__device__ __forceinline__ float bsum(float v, float* sh) {
  int lane = threadIdx.x & 63, wid = threadIdx.x >> 6;
  v = wsum(v);
  __syncthreads();
  if (lane == 0) sh[wid] = v;
  __syncthreads();
  float t = 0.f;
#pragma unroll
  for (int i = 0; i < NW; ++i) t += sh[i];
  return t;
}
template <int NW>
__device__ __forceinline__ float bmaxr(float v, float* sh) {
  int lane = threadIdx.x & 63, wid = threadIdx.x >> 6;
  v = wmaxr(v);
  __syncthreads();
  if (lane == 0) sh[wid] = v;
  __syncthreads();
  float t = sh[0];
#pragma unroll
  for (int i = 1; i < NW; ++i) t = fmaxf(t, sh[i]);
  return t;
}
__device__ __forceinline__ float sigm(float x) { return 1.0f / (1.0f + expf(-x)); }

// ---------- prep: W3 hi/lo packed tiles, A2 = keys@W2, u_norm ----------
// blocks 0..31: W3 split (ks = blk); 32..159: A2 row m; 160..415: u_norm row b
__global__ __launch_bounds__(256) void k_prep(
    const float* __restrict__ fcw, const float* __restrict__ keys,
    const float* __restrict__ ut, u16* __restrict__ W3H, u16* __restrict__ W3L,
    float* __restrict__ A2, float* __restrict__ UN) {
  __shared__ float kr[64];
  __shared__ float shs[4];
  int blk = blockIdx.x, t = threadIdx.x;
  if (blk < 32) {
    int ks = blk;
    u16 hi[32], lo[32];
#pragma unroll 8
    for (int kk = 0; kk < 32; ++kk) {
      float f = fcw[(size_t)(1600 + ks * 32 + kk) * 256 + t];
      u16 h = f2bf(f);
      hi[kk] = h;
      lo[kk] = f2bf(f - bf2f(h));
    }
    u16* dh = W3H + ks * 8192 + t * 32;
    u16* dl = W3L + ks * 8192 + t * 32;
#pragma unroll
    for (int i = 0; i < 4; ++i) {
      u16x8 vh, vl;
#pragma unroll
      for (int j = 0; j < 8; ++j) { vh[j] = hi[i * 8 + j]; vl[j] = lo[i * 8 + j]; }
      *(u16x8*)&dh[i * 8] = vh;
      *(u16x8*)&dl[i * 8] = vl;
    }
  } else if (blk < 160) {
    int m = blk - 32;
    if (t < 64) kr[t] = keys[m * 64 + t];
    __syncthreads();
    float acc = 0.f;
#pragma unroll 8
    for (int j = 0; j < 64; ++j)
      acc = fmaf(kr[j], fcw[(size_t)(1536 + j) * 256 + t], acc);
    A2[m * 256 + t] = acc;
  } else {
    int b = blk - 160;
    float v = (t < 128) ? ut[b * 128 + t] : 0.f;
    float s = bsum<4>(v * v, shs);
    float dnm = fmaxf(sqrtf(s), 1e-12f);
    if (t < 128) UN[b * 128 + t] = v / dnm;
  }
}

// ---------- A1[b,k] = fc_b[k] + xc[b]@W1 + u_norm[b]@W4 (pure f32) ----------
__global__ __launch_bounds__(256) void k_a1(
    const float* __restrict__ x, const float* __restrict__ c,
    const float* __restrict__ un, const float* __restrict__ fcw,
    const float* __restrict__ fcb, float* __restrict__ A1) {
  __shared__ float sh0[1664];
  __shared__ float sh1[1664];
  int blk = blockIdx.x, t = threadIdx.x;
  int b0 = blk * 2, b1 = blk * 2 + 1;
  for (int p = 0; p < 7; ++p) {
    int j = p * 256 + t;
    if (j < 1664) {
      sh0[j] = (j < 512) ? x[b0 * 512 + j]
             : (j < 1536) ? c[b0 * 1024 + (j - 512)] : un[b0 * 128 + (j - 1536)];
      sh1[j] = (j < 512) ? x[b1 * 512 + j]
             : (j < 1536) ? c[b1 * 1024 + (j - 512)] : un[b1 * 128 + (j - 1536)];
    }
  }
  __syncthreads();
  float a0 = fcb[t], a1v = fcb[t];
#pragma unroll 4
  for (int j = 0; j < 1536; ++j) {
    float wv = fcw[(size_t)j * 256 + t];
    a0 = fmaf(sh0[j], wv, a0);
    a1v = fmaf(sh1[j], wv, a1v);
  }
#pragma unroll 4
  for (int j = 0; j < 128; ++j) {
    float wv = fcw[(size_t)(2624 + j) * 256 + t];
    a0 = fmaf(sh0[1536 + j], wv, a0);
    a1v = fmaf(sh1[1536 + j], wv, a1v);
  }
  A1[b0 * 256 + t] = a0;
  A1[b1 * 256 + t] = a1v;
}

// ---------- K2: score GEMM, 3-pass split-bf16 MFMA + fused tanh.dot(vec_a) ----------
// grid 256 (one block per b), 512 threads. Block tile 128 rows(m) x 256 cols(hidden),
// wave tile 64x64; K=1024 in 32 steps. Writes 4 col-quarter partials of score.
__global__ __launch_bounds__(512, 2) void k2_score(
    const float* __restrict__ hmem, const u16* __restrict__ Bhp,
    const u16* __restrict__ Blp, const float* __restrict__ A1,
    const float* __restrict__ A2, const float* __restrict__ va,
    float* __restrict__ sp) {
  __shared__ __align__(16) u16 Ah[128 * 32];
  __shared__ __align__(16) u16 Al[128 * 32];
  __shared__ __align__(16) u16 Bh[256 * 32];
  __shared__ __align__(16) u16 Bl[256 * 32];
  const int b = blockIdx.x;
  const int t = threadIdx.x;
  const int lane = t & 63, w = t >> 6;
  const int q = lane >> 4, r16 = lane & 15;
  const int rh = w >> 2, cq = w & 3;

  floatx4 acc[4][4];
#pragma unroll
  for (int i = 0; i < 4; ++i)
#pragma unroll
    for (int j = 0; j < 4; ++j) acc[i][j] = (floatx4){0.f, 0.f, 0.f, 0.f};

  const int m_st = t >> 2, qh = t & 3;
  const float* aptr = hmem + ((size_t)(b * 128 + m_st)) * 1024 + qh * 8;

  float pv[8];
#pragma unroll
  for (int i = 0; i < 8; ++i) pv[i] = aptr[i];

  for (int ks = 0; ks < 32; ++ks) {
    // async-stage B (pre-split, pre-packed [col][k] tiles)
#pragma unroll
    for (int i = 0; i < 2; ++i) {
      int L = (w * 2 + i) * 1024 + lane * 16;
      gl_lds16((const char*)Bhp + (size_t)ks * 16384 + L, (char*)Bh + L);
      gl_lds16((const char*)Blp + (size_t)ks * 16384 + L, (char*)Bl + L);
    }
    // convert this step's A (hi/lo split) into LDS
    u16x8 hh, ll;
#pragma unroll
    for (int i = 0; i < 8; ++i) {
      u16 h = f2bf(pv[i]);
      float hf = bf2f(h);
      hh[i] = h;
      ll[i] = f2bf(pv[i] - hf);
    }
    *(u16x8*)&Ah[m_st * 32 + qh * 8] = hh;
    *(u16x8*)&Al[m_st * 32 + qh * 8] = ll;
    __syncthreads();
    // prefetch next A while MFMAs run
    if (ks < 31) {
      const float* np = aptr + (ks + 1) * 32;
#pragma unroll
      for (int i = 0; i < 8; ++i) pv[i] = np[i];
    }
    bf16x8 ah[4], al[4];
#pragma unroll
    for (int i = 0; i < 4; ++i) {
      int row = rh * 64 + i * 16 + r16;
      ah[i] = __builtin_bit_cast(bf16x8, *(const u16x8*)&Ah[row * 32 + q * 8]);
      al[i] = __builtin_bit_cast(bf16x8, *(const u16x8*)&Al[row * 32 + q * 8]);
    }
#pragma unroll
    for (int ct = 0; ct < 4; ++ct) {
      int col = cq * 64 + ct * 16 + r16;
      bf16x8 bh = __builtin_bit_cast(bf16x8, *(const u16x8*)&Bh[col * 32 + q * 8]);
      bf16x8 bl = __builtin_bit_cast(bf16x8, *(const u16x8*)&Bl[col * 32 + q * 8]);
#pragma unroll
      for (int i = 0; i < 4; ++i) {
        acc[i][ct] = __builtin_amdgcn_mfma_f32_16x16x32_bf16(ah[i], bh, acc[i][ct], 0, 0, 0);
        acc[i][ct] = __builtin_amdgcn_mfma_f32_16x16x32_bf16(ah[i], bl, acc[i][ct], 0, 0, 0);
        acc[i][ct] = __builtin_amdgcn_mfma_f32_16x16x32_bf16(al[i], bh, acc[i][ct], 0, 0, 0);
      }
    }
    __syncthreads();
  }
  // epilogue: pre = acc + A1[b,col] + A2[m,col]; score partial = sum_col tanh(pre)*va[col]
  float rs[4][4];
#pragma unroll
  for (int i = 0; i < 4; ++i)
#pragma unroll
    for (int r = 0; r < 4; ++r) rs[i][r] = 0.f;
#pragma unroll
  for (int ct = 0; ct < 4; ++ct) {
    int col = cq * 64 + ct * 16 + r16;
    float a1v = A1[b * 256 + col];
    float vav = va[col];
#pragma unroll
    for (int i = 0; i < 4; ++i) {
      int row0 = rh * 64 + i * 16 + q * 4;
#pragma unroll
      for (int r = 0; r < 4; ++r) {
        float pre = acc[i][ct][r] + a1v + A2[(row0 + r) * 256 + col];
        rs[i][r] += tanhf(pre) * vav;
      }
    }
  }
#pragma unroll
  for (int mask = 1; mask <= 8; mask <<= 1)
#pragma unroll
    for (int i = 0; i < 4; ++i)
#pragma unroll
      for (int r = 0; r < 4; ++r) rs[i][r] += __shfl_xor(rs[i][r], mask, 64);
  if (r16 == 0) {
#pragma unroll
    for (int i = 0; i < 4; ++i)
#pragma unroll
      for (int r = 0; r < 4; ++r) {
        int row = rh * 64 + i * 16 + q * 4 + r;
        sp[cq * 32768 + b * 128 + row] = rs[i][r];
      }
  }
}

// ---------- K3: -100*prev, LN over M, gumbel, softmax, hard weights ----------
__global__ __launch_bounds__(128) void k3_softmax(
    const float* __restrict__ sp, const float* __restrict__ prev,
    const float* __restrict__ gu, const float* __restrict__ g4,
    const float* __restrict__ b4, float* __restrict__ wgt) {
  __shared__ float shs[2];
  int b = blockIdx.x, m = threadIdx.x;
  int bm = b * 128 + m;
  float s = sp[bm] + sp[32768 + bm] + sp[65536 + bm] + sp[98304 + bm];
  s -= prev[bm] * 100.0f;
  float mu = bsum<2>(s, shs) * (1.0f / 128.0f);
  float d = s - mu;
  float var = bsum<2>(d * d, shs) * (1.0f / 128.0f);
  float sn = d / sqrtf(var + 1e-5f) * g4[m] + b4[m];
  float gv = -logf(1e-20f - logf(1e-20f + gu[bm]));
  float z = (sn + gv) * 1.0f;  // TAU = 1
  float zm = bmaxr<2>(z, shs);
  float e = expf(z - zm);
  float Zs = bsum<2>(e, shs);
  float y = e / Zs;
  float ym = bmaxr<2>(y, shs);
  float hard = (y == ym) ? 1.0f : 0.0f;
  wgt[bm] = (hard - y) + y;  // exactly 0 for non-selected rows
}

// ---------- K4: h_entry gather + build concat0 bf16 (Abuf1) ----------
__global__ __launch_bounds__(256) void k4_gather(
    const float* __restrict__ wgt, const float* __restrict__ hmem,
    const float* __restrict__ x, const float* __restrict__ c,
    float* __restrict__ he, u16* __restrict__ ab1) {
  __shared__ float wsw[128];
  int b = blockIdx.x, t = threadIdx.x;
  if (t < 128) wsw[t] = wgt[b * 128 + t];
  __syncthreads();
  float4 a;
  a.x = a.y = a.z = a.w = 0.f;
  for (int mm = 0; mm < 128; ++mm) {
    float wm = wsw[mm];
    if (wm != 0.0f) {  // wave-uniform branch, ~1 of 128 taken
      float4 v = ((const float4*)(hmem + ((size_t)(b * 128 + mm)) * 1024))[t];
      a.x = fmaf(wm, v.x, a.x);
      a.y = fmaf(wm, v.y, a.y);
      a.z = fmaf(wm, v.z, a.z);
      a.w = fmaf(wm, v.w, a.w);
    }
  }
  ((float4*)(he + (size_t)b * 1024))[t] = a;
  u16* row = ab1 + (size_t)b * 2560;
  if (t < 128) {
    float4 xv = ((const float4*)(x + (size_t)b * 512))[t];
    u16x4 o = {f2bf(xv.x), f2bf(xv.y), f2bf(xv.z), f2bf(xv.w)};
    *(u16x4*)&row[t * 4] = o;
  }
  {
    float4 cv = ((const float4*)(c + (size_t)b * 1024))[t];
    u16x4 o = {f2bf(cv.x), f2bf(cv.y), f2bf(cv.z), f2bf(cv.w)};
    *(u16x4*)&row[512 + t * 4] = o;
  }
  {
    u16x4 o = {f2bf(a.x), f2bf(a.y), f2bf(a.z), f2bf(a.w)};
    *(u16x4*)&row[1536 + t * 4] = o;
  }
}

// ---------- cell GEMM: Z += Abf(bf16) @ W(f32, converted in-kernel) ----------
// block tile 256 rows x 64 cols; grid = nblk*splitk; f32 atomicAdd epilogue.
__global__ __launch_bounds__(256) void gemm_cell(
    const u16* __restrict__ Abf, const float* __restrict__ W,
    float* __restrict__ Z, int N, int nblk, int nsteps) {
  __shared__ __align__(16) u16 Asm[256 * 32];
  __shared__ __align__(16) float Bf[32 * 64];
  __shared__ __align__(16) u16 Bsm[64 * 40];  // col stride 40 (80B) -> conflict-free
  int cb = blockIdx.x % nblk;
  int kc = blockIdx.x / nblk;
  int t = threadIdx.x, lane = t & 63, w = t >> 6;
  int q = lane >> 4, r16 = lane & 15;
  floatx4 acc[4][4];
#pragma unroll
  for (int i = 0; i < 4; ++i)
#pragma unroll
    for (int j = 0; j < 4; ++j) acc[i][j] = (floatx4){0.f, 0.f, 0.f, 0.f};
  int k0 = kc * nsteps * 32;
  for (int ks = 0; ks < nsteps; ++ks) {
    int k = k0 + ks * 32;
    // A: 256x32 bf16 = 16KB DMA
#pragma unroll
    for (int i = 0; i < 4; ++i) {
      int L = (w * 4 + i) * 1024 + lane * 16;
      int row = L >> 6, off = L & 63;
      gl_lds16((const char*)Abf + (size_t)row * 5120 + k * 2 + off, (char*)Asm + L);
    }
    // B: 32x64 f32 = 8KB DMA (natural [k][col])
#pragma unroll
    for (int i = 0; i < 2; ++i) {
      int L = (w * 2 + i) * 1024 + lane * 16;
      int kr = L >> 8, off = L & 255;
      gl_lds16((const char*)W + ((size_t)(k + kr) * N + cb * 64) * 4 + off, (char*)Bf + L);
    }
    __syncthreads();
    // transpose-convert B -> [col][k] bf16
    {
      int cc = t & 63, p = t >> 6;
      u16x8 hh;
#pragma unroll
      for (int i2 = 0; i2 < 8; ++i2) hh[i2] = f2bf(Bf[(p * 8 + i2) * 64 + cc]);
      *(u16x8*)&Bsm[cc * 40 + p * 8] = hh;
    }
    __syncthreads();
    bf16x8 af[4];
#pragma unroll
    for (int i = 0; i < 4; ++i) {
      int row = w * 64 + i * 16 + r16;
      af[i] = __builtin_bit_cast(bf16x8, *(const u16x8*)&Asm[row * 32 + q * 8]);
    }
#pragma unroll
    for (int ct = 0; ct < 4; ++ct) {
      int col = ct * 16 + r16;
      bf16x8 bb = __builtin_bit_cast(bf16x8, *(const u16x8*)&Bsm[col * 40 + q * 8]);
#pragma unroll
      for (int i = 0; i < 4; ++i)
        acc[i][ct] = __builtin_amdgcn_mfma_f32_16x16x32_bf16(af[i], bb, acc[i][ct], 0, 0, 0);
    }
    __syncthreads();
  }
#pragma unroll
  for (int ct = 0; ct < 4; ++ct)
#pragma unroll
    for (int i = 0; i < 4; ++i)
#pragma unroll
      for (int r = 0; r < 4; ++r) {
        int col = cb * 64 + ct * 16 + r16;
        int row = w * 64 + i * 16 + q * 4 + r;
        atomicAdd(&Z[(size_t)row * N + col], acc[i][ct][r]);
      }
}

// ---------- K5b: LN3(2 chunks)+sigmoid gate, build gated Abuf2 ----------
__global__ __launch_bounds__(256) void k5b(
    const float* __restrict__ Z1, const float* __restrict__ bias1,
    const float* __restrict__ x, const float* __restrict__ c,
    const float* __restrict__ he, const float* __restrict__ g3,
    const float* __restrict__ b3, u16* __restrict__ ab2) {
  __shared__ float shs[4];
  int b = blockIdx.x, t = threadIdx.x;
  const float4* zp = (const float4*)(Z1 + (size_t)b * 2048);
  const float4* bp = (const float4*)bias1;
  float4 z0v = zp[t], z1v = zp[256 + t];
  float4 q0 = bp[t], q1 = bp[256 + t];
  float za[4] = {z0v.x + q0.x, z0v.y + q0.y, z0v.z + q0.z, z0v.w + q0.w};
  float zb[4] = {z1v.x + q1.x, z1v.y + q1.y, z1v.z + q1.z, z1v.w + q1.w};
  float g1a[4], g1b[4];
  {
    float s = za[0] + za[1] + za[2] + za[3];
    float mu = bsum<4>(s, shs) * (1.0f / 1024.0f);
    float ss = 0.f;
#pragma unroll
    for (int i = 0; i < 4; ++i) { float d = za[i] - mu; ss += d * d; }
    float var = bsum<4>(ss, shs) * (1.0f / 1024.0f);
    float r = sqrtf(var + 1e-5f);
    float4 gv = ((const float4*)g3)[t];
    float4 bv = ((const float4*)b3)[t];
    g1a[0] = sigm((za[0] - mu) / r * gv.x + bv.x);
    g1a[1] = sigm((za[1] - mu) / r * gv.y + bv.y);
    g1a[2] = sigm((za[2] - mu) / r * gv.z + bv.z);
    g1a[3] = sigm((za[3] - mu) / r * gv.w + bv.w);
  }
  {
    float s = zb[0] + zb[1] + zb[2] + zb[3];
    float mu = bsum<4>(s, shs) * (1.0f / 1024.0f);
    float ss = 0.f;
#pragma unroll
    for (int i = 0; i < 4; ++i) { float d = zb[i] - mu; ss += d * d; }
    float var = bsum<4>(ss, shs) * (1.0f / 1024.0f);
    float r = sqrtf(var + 1e-5f);
    float4 gv = ((const float4*)g3)[256 + t];
    float4 bv = ((const float4*)b3)[256 + t];
    g1b[0] = sigm((zb[0] - mu) / r * gv.x + bv.x);
    g1b[1] = sigm((zb[1] - mu) / r * gv.y + bv.y);
    g1b[2] = sigm((zb[2] - mu) / r * gv.z + bv.z);
    g1b[3] = sigm((zb[3] - mu) / r * gv.w + bv.w);
  }
  u16* row = ab2 + (size_t)b * 2560;
  if (t < 128) {
    float4 xv = ((const float4*)(x + (size_t)b * 512))[t];
    u16x4 o = {f2bf(xv.x), f2bf(xv.y), f2bf(xv.z), f2bf(xv.w)};
    *(u16x4*)&row[t * 4] = o;
  }
  {
    float4 cv = ((const float4*)(c + (size_t)b * 1024))[t];
    u16x4 o = {f2bf(cv.x * g1a[0]), f2bf(cv.y * g1a[1]), f2bf(cv.z * g1a[2]), f2bf(cv.w * g1a[3])};
    *(u16x4*)&row[512 + t * 4] = o;
  }
  {
    float4 hv = ((const float4*)(he + (size_t)b * 1024))[t];
    u16x4 o = {f2bf(hv.x * g1b[0]), f2bf(hv.y * g1b[1]), f2bf(hv.z * g1b[2]), f2bf(hv.w * g1b[3])};
    *(u16x4*)&row[1536 + t * 4] = o;
  }
}

// ---------- K5d: LN1(5 chunks), cell update, LN2, outputs ----------
__global__ __launch_bounds__(256) void k5d(
    const float* __restrict__ Z2, const float* __restrict__ bias,
    const float* __restrict__ c, const float* __restrict__ he,
    const float* __restrict__ g1, const float* __restrict__ b1,
    const float* __restrict__ g2, const float* __restrict__ b2,
    float* __restrict__ out) {
  __shared__ float shs[4];
  int b = blockIdx.x, t = threadIdx.x;
  const float4* zp = (const float4*)(Z2 + (size_t)b * 5120);
  const float4* bp = (const float4*)bias;
  float z[5][4];
#pragma unroll
  for (int ci = 0; ci < 5; ++ci) {
    float4 v = zp[ci * 256 + t];
    float4 bb = bp[ci * 256 + t];
    z[ci][0] = v.x + bb.x; z[ci][1] = v.y + bb.y;
    z[ci][2] = v.z + bb.z; z[ci][3] = v.w + bb.w;
  }
#pragma unroll
  for (int ci = 0; ci < 5; ++ci) {
    float s = z[ci][0] + z[ci][1] + z[ci][2] + z[ci][3];
    float mu = bsum<4>(s, shs) * (1.0f / 1024.0f);
    float ss = 0.f;
#pragma unroll
    for (int i = 0; i < 4; ++i) { float d = z[ci][i] - mu; ss += d * d; }
    float var = bsum<4>(ss, shs) * (1.0f / 1024.0f);
    float r = sqrtf(var + 1e-5f);
    float4 gv = ((const float4*)g1)[ci * 256 + t];
    float4 bv = ((const float4*)b1)[ci * 256 + t];
    z[ci][0] = (z[ci][0] - mu) / r * gv.x + bv.x;
    z[ci][1] = (z[ci][1] - mu) / r * gv.y + bv.y;
    z[ci][2] = (z[ci][2] - mu) / r * gv.z + bv.z;
    z[ci][3] = (z[ci][3] - mu) / r * gv.w + bv.w;
  }
  float4 cv = ((const float4*)(c + (size_t)b * 1024))[t];
  float cvv[4] = {cv.x, cv.y, cv.z, cv.w};
  float nc[4];
#pragma unroll
  for (int i = 0; i < 4; ++i)
    nc[i] = cvv[i] * sigm(z[2][i] + 1.0f) + sigm(z[0][i]) * tanhf(z[1][i]);
  float s = nc[0] + nc[1] + nc[2] + nc[3];
  float mu = bsum<4>(s, shs) * (1.0f / 1024.0f);
  float ss = 0.f;
#pragma unroll
  for (int i = 0; i < 4; ++i) { float d = nc[i] - mu; ss += d * d; }
  float var = bsum<4>(ss, shs) * (1.0f / 1024.0f);
  float r2 = sqrtf(var + 1e-5f);
  float4 g2v = ((const float4*)g2)[t];
  float4 b2v = ((const float4*)b2)[t];
  float g2a[4] = {g2v.x, g2v.y, g2v.z, g2v.w};
  float b2a[4] = {b2v.x, b2v.y, b2v.z, b2v.w};
  float4 hv = ((const float4*)(he + (size_t)b * 1024))[t];
  float hva[4] = {hv.x, hv.y, hv.z, hv.w};
  float4 o1, o2;
  float nh[4], rr[4];
#pragma unroll
  for (int i = 0; i < 4; ++i) {
    float ncn = (nc[i] - mu) / r2 * g2a[i] + b2a[i];
    nh[i] = tanhf(ncn) * sigm(z[3][i]);
    rr[i] = tanhf(hva[i]) * sigm(z[4][i]);
  }
  o1.x = nh[0]; o1.y = nh[1]; o1.z = nh[2]; o1.w = nh[3];
  o2.x = rr[0]; o2.y = rr[1]; o2.z = rr[2]; o2.w = rr[3];
  ((float4*)(out + (size_t)b * 2048))[t] = o1;
  ((float4*)(out + (size_t)b * 2048 + 1024))[t] = o2;
}

// ---------- launch ----------
extern "C" void kernel_launch(void* const* d_in, const int* in_sizes, int n_in,
                              void* d_out, int out_size, void* d_ws, size_t ws_size,
                              hipStream_t stream) {
  const float* x = (const float*)d_in[0];
  const float* c = (const float*)d_in[1];
  const float* hmem = (const float*)d_in[2];
  const float* ut = (const float*)d_in[3];
  const float* prev = (const float*)d_in[4];
  const float* gu = (const float*)d_in[5];
  const float* keys = (const float*)d_in[6];
  const float* veca = (const float*)d_in[7];
  const float* fcw = (const float*)d_in[8];
  const float* fcb = (const float*)d_in[9];
  const float* Wf = (const float*)d_in[10];
  const float* bias = (const float*)d_in[11];
  const float* Wf1 = (const float*)d_in[12];
  const float* bias1 = (const float*)d_in[13];
  const float* ln1g = (const float*)d_in[14];
  const float* ln1b = (const float*)d_in[15];
  const float* ln2g = (const float*)d_in[16];
  const float* ln2b = (const float*)d_in[17];
  const float* ln3g = (const float*)d_in[18];
  const float* ln3b = (const float*)d_in[19];
  const float* ln4g = (const float*)d_in[20];
  const float* ln4b = (const float*)d_in[21];

  char* ws = (char*)d_ws;
  float* UN = (float*)(ws + 0);            // 128 KB
  float* A2 = (float*)(ws + 131072);       // 128 KB
  float* A1 = (float*)(ws + 262144);       // 256 KB
  u16* W3H = (u16*)(ws + 524288);          // 512 KB
  u16* W3L = (u16*)(ws + 1048576);         // 512 KB
  float* SP = (float*)(ws + 1572864);      // 512 KB (4 col-quarter partials)
  float* WGT = (float*)(ws + 2097152);     // 128 KB
  float* HE = (float*)(ws + 2228224);      // 1 MB
  u16* AB1 = (u16*)(ws + 3276800);         // 1.25 MB
  u16* AB2 = (u16*)(ws + 4587520);         // 1.25 MB
  float* Z1 = (float*)(ws + 5898240);      // 2 MB
  float* Z2 = (float*)(ws + 7995392);      // 5 MB  -> total ~12.6 MB

  hipMemsetAsync(Z1, 0, (size_t)256 * 2048 * 4, stream);
  hipMemsetAsync(Z2, 0, (size_t)256 * 5120 * 4, stream);
  k_prep<<<416, 256, 0, stream>>>(fcw, keys, ut, W3H, W3L, A2, UN);
  k_a1<<<128, 256, 0, stream>>>(x, c, UN, fcw, fcb, A1);
  k2_score<<<256, 512, 0, stream>>>(hmem, W3H, W3L, A1, A2, veca, SP);
  k3_softmax<<<256, 128, 0, stream>>>(SP, prev, gu, ln4g, ln4b, WGT);
  k4_gather<<<256, 256, 0, stream>>>(WGT, hmem, x, c, HE, AB1);
  gemm_cell<<<32 * 8, 256, 0, stream>>>(AB1, Wf1, Z1, 2048, 32, 10);
  k5b<<<256, 256, 0, stream>>>(Z1, bias1, x, c, HE, ln3g, ln3b, AB2);
  gemm_cell<<<80 * 4, 256, 0, stream>>>(AB2, Wf, Z2, 5120, 80, 20);
  k5d<<<256, 256, 0, stream>>>(Z2, bias, c, HE, ln1g, ln1b, ln2g, ln2b, (float*)d_out);
}

// Round 2
// 449.563 us; speedup vs baseline: 1.3570x; 1.3570x over previous
//
#include <hip/hip_runtime.h>
#include <cstdint>
#include <cstddef>

typedef unsigned short u16;
typedef float floatx4 __attribute__((ext_vector_type(4)));
typedef __bf16 bf16x8 __attribute__((ext_vector_type(8)));
typedef unsigned short u16x8 __attribute__((ext_vector_type(8)));
typedef unsigned short u16x4 __attribute__((ext_vector_type(4)));

// ---------- helpers ----------
__device__ __forceinline__ u16 f2bf(float f) {
  unsigned u = __float_as_uint(f);
  unsigned r = u + 0x7FFFu + ((u >> 16) & 1u);   // RNE
  return (u16)(r >> 16);
}
__device__ __forceinline__ float bf2f(u16 h) {
  return __uint_as_float(((unsigned)h) << 16);
}
__device__ __forceinline__ void gl_lds16(const void* g, void* l) {
  __builtin_amdgcn_global_load_lds(
      (const __attribute__((address_space(1))) unsigned int*)g,
      (__attribute__((address_space(3))) unsigned int*)l, 16, 0, 0);
}
__device__ __forceinline__ float wsum(float v) {
#pragma unroll
  for (int m = 32; m > 0; m >>= 1) v += __shfl_xor(v, m, 64);
  return v;
}
__device__ __forceinline__ float wmaxr(float v) {
#pragma unroll
  for (int m = 32; m > 0; m >>= 1) v = fmaxf(v, __shfl_xor(v, m, 64));
  return v;
}
template <int NW>
__device__ __forceinline__ float bsum(float v, float* sh) {
  int lane = threadIdx.x & 63, wid = threadIdx.x >> 6;
  v = wsum(v);
  __syncthreads();
  if (lane == 0) sh[wid] = v;
  __syncthreads();
  float t = 0.f;
#pragma unroll
  for (int i = 0; i < NW; ++i) t += sh[i];
  return t;
}
template <int NW>
__device__ __forceinline__ float bmaxr(float v, float* sh) {
  int lane = threadIdx.x & 63, wid = threadIdx.x >> 6;
  v = wmaxr(v);
  __syncthreads();
  if (lane == 0) sh[wid] = v;
  __syncthreads();
  float t = sh[0];
#pragma unroll
  for (int i = 1; i < NW; ++i) t = fmaxf(t, sh[i]);
  return t;
}
__device__ __forceinline__ float sigm(float x) { return 1.0f / (1.0f + expf(-x)); }

// ---------- prep: W3 hi/lo packed tiles, A2 = fc_b + keys@W2, u_norm ----------
// blocks 0..31: W3 split (ks = blk); 32..159: A2 row m; 160..415: u_norm row b
__global__ __launch_bounds__(256) void k_prep(
    const float* __restrict__ fcw, const float* __restrict__ keys,
    const float* __restrict__ ut, const float* __restrict__ fcb,
    u16* __restrict__ W3H, u16* __restrict__ W3L,
    float* __restrict__ A2, float* __restrict__ UN) {
  __shared__ float kr[64];
  __shared__ float shs[4];
  int blk = blockIdx.x, t = threadIdx.x;
  if (blk < 32) {
    int ks = blk;
    u16 hi[32], lo[32];
#pragma unroll 8
    for (int kk = 0; kk < 32; ++kk) {
      float f = fcw[(size_t)(1600 + ks * 32 + kk) * 256 + t];
      u16 h = f2bf(f);
      hi[kk] = h;
      lo[kk] = f2bf(f - bf2f(h));
    }
    u16* dh = W3H + ks * 8192 + t * 32;
    u16* dl = W3L + ks * 8192 + t * 32;
#pragma unroll
    for (int i = 0; i < 4; ++i) {
      u16x8 vh, vl;
#pragma unroll
      for (int j = 0; j < 8; ++j) { vh[j] = hi[i * 8 + j]; vl[j] = lo[i * 8 + j]; }
      *(u16x8*)&dh[i * 8] = vh;
      *(u16x8*)&dl[i * 8] = vl;
    }
  } else if (blk < 160) {
    int m = blk - 32;
    if (t < 64) kr[t] = keys[m * 64 + t];
    __syncthreads();
    float acc = fcb[t];   // fold fc_b here (A1 is pure atomic accumulation now)
#pragma unroll 8
    for (int j = 0; j < 64; ++j)
      acc = fmaf(kr[j], fcw[(size_t)(1536 + j) * 256 + t], acc);
    A2[m * 256 + t] = acc;
  } else {
    int b = blk - 160;
    float v = (t < 128) ? ut[b * 128 + t] : 0.f;
    float s = bsum<4>(v * v, shs);
    float dnm = fmaxf(sqrtf(s), 1e-12f);
    if (t < 128) UN[b * 128 + t] = v / dnm;
  }
}

// ---------- A1[b,k] += xc_un[b]@W1/W4 : split-K f32, atomic epilogue ----------
// grid = 32 b-groups * 26 k-chunks = 832 blocks; chunk width 64 never
// straddles the x/c/un boundaries (512,1536) so remap is chunk-uniform.
__global__ __launch_bounds__(256) void k_a1(
    const float* __restrict__ x, const float* __restrict__ c,
    const float* __restrict__ un, const float* __restrict__ fcw,
    float* __restrict__ A1) {
  __shared__ float sh[512];
  int kc = blockIdx.x % 26;
  int bg = blockIdx.x / 26;
  int t = threadIdx.x;
  int g0 = kc * 64;
  int row_base = (g0 < 1536) ? g0 : g0 + 1088;  // skip keys(64)+hmem(1024) rows
#pragma unroll
  for (int p = 0; p < 2; ++p) {
    int idx = p * 256 + t;
    int bl = idx >> 6, j = idx & 63;
    int b = bg * 8 + bl;
    int g = g0 + j;
    float v;
    if (g < 512) v = x[b * 512 + g];
    else if (g < 1536) v = c[b * 1024 + (g - 512)];
    else v = un[b * 128 + (g - 1536)];
    sh[idx] = v;
  }
  __syncthreads();
  float acc[8];
#pragma unroll
  for (int i = 0; i < 8; ++i) acc[i] = 0.f;
#pragma unroll 4
  for (int j = 0; j < 64; ++j) {
    float wv = fcw[(size_t)(row_base + j) * 256 + t];
#pragma unroll
    for (int bl = 0; bl < 8; ++bl)
      acc[bl] = fmaf(sh[bl * 64 + j], wv, acc[bl]);
  }
#pragma unroll
  for (int bl = 0; bl < 8; ++bl)
    atomicAdd(&A1[(bg * 8 + bl) * 256 + t], acc[bl]);
}

// ---------- K2: score GEMM, 3-pass split-bf16 MFMA + fused tanh.dot(vec_a) ----------
__global__ __launch_bounds__(512, 2) void k2_score(
    const float* __restrict__ hmem, const u16* __restrict__ Bhp,
    const u16* __restrict__ Blp, const float* __restrict__ A1,
    const float* __restrict__ A2, const float* __restrict__ va,
    float* __restrict__ sp) {
  __shared__ __align__(16) u16 Ah[128 * 32];
  __shared__ __align__(16) u16 Al[128 * 32];
  __shared__ __align__(16) u16 Bh[256 * 32];
  __shared__ __align__(16) u16 Bl[256 * 32];
  const int b = blockIdx.x;
  const int t = threadIdx.x;
  const int lane = t & 63, w = t >> 6;
  const int q = lane >> 4, r16 = lane & 15;
  const int rh = w >> 2, cq = w & 3;

  floatx4 acc[4][4];
#pragma unroll
  for (int i = 0; i < 4; ++i)
#pragma unroll
    for (int j = 0; j < 4; ++j) acc[i][j] = (floatx4){0.f, 0.f, 0.f, 0.f};

  const int m_st = t >> 2, qh = t & 3;
  const float* aptr = hmem + ((size_t)(b * 128 + m_st)) * 1024 + qh * 8;

  float pv[8];
#pragma unroll
  for (int i = 0; i < 8; ++i) pv[i] = aptr[i];

  for (int ks = 0; ks < 32; ++ks) {
#pragma unroll
    for (int i = 0; i < 2; ++i) {
      int L = (w * 2 + i) * 1024 + lane * 16;
      gl_lds16((const char*)Bhp + (size_t)ks * 16384 + L, (char*)Bh + L);
      gl_lds16((const char*)Blp + (size_t)ks * 16384 + L, (char*)Bl + L);
    }
    u16x8 hh, ll;
#pragma unroll
    for (int i = 0; i < 8; ++i) {
      u16 h = f2bf(pv[i]);
      float hf = bf2f(h);
      hh[i] = h;
      ll[i] = f2bf(pv[i] - hf);
    }
    *(u16x8*)&Ah[m_st * 32 + qh * 8] = hh;
    *(u16x8*)&Al[m_st * 32 + qh * 8] = ll;
    __syncthreads();
    if (ks < 31) {
      const float* np = aptr + (ks + 1) * 32;
#pragma unroll
      for (int i = 0; i < 8; ++i) pv[i] = np[i];
    }
    bf16x8 ah[4], al[4];
#pragma unroll
    for (int i = 0; i < 4; ++i) {
      int row = rh * 64 + i * 16 + r16;
      ah[i] = __builtin_bit_cast(bf16x8, *(const u16x8*)&Ah[row * 32 + q * 8]);
      al[i] = __builtin_bit_cast(bf16x8, *(const u16x8*)&Al[row * 32 + q * 8]);
    }
#pragma unroll
    for (int ct = 0; ct < 4; ++ct) {
      int col = cq * 64 + ct * 16 + r16;
      bf16x8 bh = __builtin_bit_cast(bf16x8, *(const u16x8*)&Bh[col * 32 + q * 8]);
      bf16x8 bl = __builtin_bit_cast(bf16x8, *(const u16x8*)&Bl[col * 32 + q * 8]);
#pragma unroll
      for (int i = 0; i < 4; ++i) {
        acc[i][ct] = __builtin_amdgcn_mfma_f32_16x16x32_bf16(ah[i], bh, acc[i][ct], 0, 0, 0);
        acc[i][ct] = __builtin_amdgcn_mfma_f32_16x16x32_bf16(ah[i], bl, acc[i][ct], 0, 0, 0);
        acc[i][ct] = __builtin_amdgcn_mfma_f32_16x16x32_bf16(al[i], bh, acc[i][ct], 0, 0, 0);
      }
    }
    __syncthreads();
  }
  float rs[4][4];
#pragma unroll
  for (int i = 0; i < 4; ++i)
#pragma unroll
    for (int r = 0; r < 4; ++r) rs[i][r] = 0.f;
#pragma unroll
  for (int ct = 0; ct < 4; ++ct) {
    int col = cq * 64 + ct * 16 + r16;
    float a1v = A1[b * 256 + col];
    float vav = va[col];
#pragma unroll
    for (int i = 0; i < 4; ++i) {
      int row0 = rh * 64 + i * 16 + q * 4;
#pragma unroll
      for (int r = 0; r < 4; ++r) {
        float pre = acc[i][ct][r] + a1v + A2[(row0 + r) * 256 + col];
        rs[i][r] += tanhf(pre) * vav;
      }
    }
  }
#pragma unroll
  for (int mask = 1; mask <= 8; mask <<= 1)
#pragma unroll
    for (int i = 0; i < 4; ++i)
#pragma unroll
      for (int r = 0; r < 4; ++r) rs[i][r] += __shfl_xor(rs[i][r], mask, 64);
  if (r16 == 0) {
#pragma unroll
    for (int i = 0; i < 4; ++i)
#pragma unroll
      for (int r = 0; r < 4; ++r) {
        int row = rh * 64 + i * 16 + q * 4 + r;
        sp[cq * 32768 + b * 128 + row] = rs[i][r];
      }
  }
}

// ---------- K3: -100*prev, LN over M, gumbel, softmax, hard weights ----------
__global__ __launch_bounds__(128) void k3_softmax(
    const float* __restrict__ sp, const float* __restrict__ prev,
    const float* __restrict__ gu, const float* __restrict__ g4,
    const float* __restrict__ b4, float* __restrict__ wgt) {
  __shared__ float shs[2];
  int b = blockIdx.x, m = threadIdx.x;
  int bm = b * 128 + m;
  float s = sp[bm] + sp[32768 + bm] + sp[65536 + bm] + sp[98304 + bm];
  s -= prev[bm] * 100.0f;
  float mu = bsum<2>(s, shs) * (1.0f / 128.0f);
  float d = s - mu;
  float var = bsum<2>(d * d, shs) * (1.0f / 128.0f);
  float sn = d / sqrtf(var + 1e-5f) * g4[m] + b4[m];
  float gv = -logf(1e-20f - logf(1e-20f + gu[bm]));
  float z = (sn + gv) * 1.0f;  // TAU = 1
  float zm = bmaxr<2>(z, shs);
  float e = expf(z - zm);
  float Zs = bsum<2>(e, shs);
  float y = e / Zs;
  float ym = bmaxr<2>(y, shs);
  float hard = (y == ym) ? 1.0f : 0.0f;
  wgt[bm] = (hard - y) + y;  // exactly 0 for non-selected rows
}

// ---------- K4: h_entry gather + build concat0 bf16 (Abuf1) ----------
__global__ __launch_bounds__(256) void k4_gather(
    const float* __restrict__ wgt, const float* __restrict__ hmem,
    const float* __restrict__ x, const float* __restrict__ c,
    float* __restrict__ he, u16* __restrict__ ab1) {
  __shared__ float wsw[128];
  int b = blockIdx.x, t = threadIdx.x;
  if (t < 128) wsw[t] = wgt[b * 128 + t];
  __syncthreads();
  float4 a;
  a.x = a.y = a.z = a.w = 0.f;
  for (int mm = 0; mm < 128; ++mm) {
    float wm = wsw[mm];
    if (wm != 0.0f) {
      float4 v = ((const float4*)(hmem + ((size_t)(b * 128 + mm)) * 1024))[t];
      a.x = fmaf(wm, v.x, a.x);
      a.y = fmaf(wm, v.y, a.y);
      a.z = fmaf(wm, v.z, a.z);
      a.w = fmaf(wm, v.w, a.w);
    }
  }
  ((float4*)(he + (size_t)b * 1024))[t] = a;
  u16* row = ab1 + (size_t)b * 2560;
  if (t < 128) {
    float4 xv = ((const float4*)(x + (size_t)b * 512))[t];
    u16x4 o = {f2bf(xv.x), f2bf(xv.y), f2bf(xv.z), f2bf(xv.w)};
    *(u16x4*)&row[t * 4] = o;
  }
  {
    float4 cv = ((const float4*)(c + (size_t)b * 1024))[t];
    u16x4 o = {f2bf(cv.x), f2bf(cv.y), f2bf(cv.z), f2bf(cv.w)};
    *(u16x4*)&row[512 + t * 4] = o;
  }
  {
    u16x4 o = {f2bf(a.x), f2bf(a.y), f2bf(a.z), f2bf(a.w)};
    *(u16x4*)&row[1536 + t * 4] = o;
  }
}

// ---------- cell GEMM: Z += Abf(bf16) @ W(f32, converted in-kernel) ----------
__global__ __launch_bounds__(256) void gemm_cell(
    const u16* __restrict__ Abf, const float* __restrict__ W,
    float* __restrict__ Z, int N, int nblk, int nsteps) {
  __shared__ __align__(16) u16 Asm[256 * 32];
  __shared__ __align__(16) float Bf[32 * 64];
  __shared__ __align__(16) u16 Bsm[64 * 40];
  int cb = blockIdx.x % nblk;
  int kc = blockIdx.x / nblk;
  int t = threadIdx.x, lane = t & 63, w = t >> 6;
  int q = lane >> 4, r16 = lane & 15;
  floatx4 acc[4][4];
#pragma unroll
  for (int i = 0; i < 4; ++i)
#pragma unroll
    for (int j = 0; j < 4; ++j) acc[i][j] = (floatx4){0.f, 0.f, 0.f, 0.f};
  int k0 = kc * nsteps * 32;
  for (int ks = 0; ks < nsteps; ++ks) {
    int k = k0 + ks * 32;
#pragma unroll
    for (int i = 0; i < 4; ++i) {
      int L = (w * 4 + i) * 1024 + lane * 16;
      int row = L >> 6, off = L & 63;
      gl_lds16((const char*)Abf + (size_t)row * 5120 + k * 2 + off, (char*)Asm + L);
    }
#pragma unroll
    for (int i = 0; i < 2; ++i) {
      int L = (w * 2 + i) * 1024 + lane * 16;
      int kr = L >> 8, off = L & 255;
      gl_lds16((const char*)W + ((size_t)(k + kr) * N + cb * 64) * 4 + off, (char*)Bf + L);
    }
    __syncthreads();
    {
      int cc = t & 63, p = t >> 6;
      u16x8 hh;
#pragma unroll
      for (int i2 = 0; i2 < 8; ++i2) hh[i2] = f2bf(Bf[(p * 8 + i2) * 64 + cc]);
      *(u16x8*)&Bsm[cc * 40 + p * 8] = hh;
    }
    __syncthreads();
    bf16x8 af[4];
#pragma unroll
    for (int i = 0; i < 4; ++i) {
      int row = w * 64 + i * 16 + r16;
      af[i] = __builtin_bit_cast(bf16x8, *(const u16x8*)&Asm[row * 32 + q * 8]);
    }
#pragma unroll
    for (int ct = 0; ct < 4; ++ct) {
      int col = ct * 16 + r16;
      bf16x8 bb = __builtin_bit_cast(bf16x8, *(const u16x8*)&Bsm[col * 40 + q * 8]);
#pragma unroll
      for (int i = 0; i < 4; ++i)
        acc[i][ct] = __builtin_amdgcn_mfma_f32_16x16x32_bf16(af[i], bb, acc[i][ct], 0, 0, 0);
    }
    __syncthreads();
  }
#pragma unroll
  for (int ct = 0; ct < 4; ++ct)
#pragma unroll
    for (int i = 0; i < 4; ++i)
#pragma unroll
      for (int r = 0; r < 4; ++r) {
        int col = cb * 64 + ct * 16 + r16;
        int row = w * 64 + i * 16 + q * 4 + r;
        atomicAdd(&Z[(size_t)row * N + col], acc[i][ct][r]);
      }
}

// ---------- K5b: LN3(2 chunks)+sigmoid gate, build gated Abuf2 ----------
__global__ __launch_bounds__(256) void k5b(
    const float* __restrict__ Z1, const float* __restrict__ bias1,
    const float* __restrict__ x, const float* __restrict__ c,
    const float* __restrict__ he, const float* __restrict__ g3,
    const float* __restrict__ b3, u16* __restrict__ ab2) {
  __shared__ float shs[4];
  int b = blockIdx.x, t = threadIdx.x;
  const float4* zp = (const float4*)(Z1 + (size_t)b * 2048);
  const float4* bp = (const float4*)bias1;
  float4 z0v = zp[t], z1v = zp[256 + t];
  float4 q0 = bp[t], q1 = bp[256 + t];
  float za[4] = {z0v.x + q0.x, z0v.y + q0.y, z0v.z + q0.z, z0v.w + q0.w};
  float zb[4] = {z1v.x + q1.x, z1v.y + q1.y, z1v.z + q1.z, z1v.w + q1.w};
  float g1a[4], g1b[4];
  {
    float s = za[0] + za[1] + za[2] + za[3];
    float mu = bsum<4>(s, shs) * (1.0f / 1024.0f);
    float ss = 0.f;
#pragma unroll
    for (int i = 0; i < 4; ++i) { float d = za[i] - mu; ss += d * d; }
    float var = bsum<4>(ss, shs) * (1.0f / 1024.0f);
    float r = sqrtf(var + 1e-5f);
    float4 gv = ((const float4*)g3)[t];
    float4 bv = ((const float4*)b3)[t];
    g1a[0] = sigm((za[0] - mu) / r * gv.x + bv.x);
    g1a[1] = sigm((za[1] - mu) / r * gv.y + bv.y);
    g1a[2] = sigm((za[2] - mu) / r * gv.z + bv.z);
    g1a[3] = sigm((za[3] - mu) / r * gv.w + bv.w);
  }
  {
    float s = zb[0] + zb[1] + zb[2] + zb[3];
    float mu = bsum<4>(s, shs) * (1.0f / 1024.0f);
    float ss = 0.f;
#pragma unroll
    for (int i = 0; i < 4; ++i) { float d = zb[i] - mu; ss += d * d; }
    float var = bsum<4>(ss, shs) * (1.0f / 1024.0f);
    float r = sqrtf(var + 1e-5f);
    float4 gv = ((const float4*)g3)[256 + t];
    float4 bv = ((const float4*)b3)[256 + t];
    g1b[0] = sigm((zb[0] - mu) / r * gv.x + bv.x);
    g1b[1] = sigm((zb[1] - mu) / r * gv.y + bv.y);
    g1b[2] = sigm((zb[2] - mu) / r * gv.z + bv.z);
    g1b[3] = sigm((zb[3] - mu) / r * gv.w + bv.w);
  }
  u16* row = ab2 + (size_t)b * 2560;
  if (t < 128) {
    float4 xv = ((const float4*)(x + (size_t)b * 512))[t];
    u16x4 o = {f2bf(xv.x), f2bf(xv.y), f2bf(xv.z), f2bf(xv.w)};
    *(u16x4*)&row[t * 4] = o;
  }
  {
    float4 cv = ((const float4*)(c + (size_t)b * 1024))[t];
    u16x4 o = {f2bf(cv.x * g1a[0]), f2bf(cv.y * g1a[1]), f2bf(cv.z * g1a[2]), f2bf(cv.w * g1a[3])};
    *(u16x4*)&row[512 + t * 4] = o;
  }
  {
    float4 hv = ((const float4*)(he + (size_t)b * 1024))[t];
    u16x4 o = {f2bf(hv.x * g1b[0]), f2bf(hv.y * g1b[1]), f2bf(hv.z * g1b[2]), f2bf(hv.w * g1b[3])};
    *(u16x4*)&row[1536 + t * 4] = o;
  }
}

// ---------- K5d: LN1(5 chunks), cell update, LN2, outputs ----------
__global__ __launch_bounds__(256) void k5d(
    const float* __restrict__ Z2, const float* __restrict__ bias,
    const float* __restrict__ c, const float* __restrict__ he,
    const float* __restrict__ g1, const float* __restrict__ b1,
    const float* __restrict__ g2, const float* __restrict__ b2,
    float* __restrict__ out) {
  __shared__ float shs[4];
  int b = blockIdx.x, t = threadIdx.x;
  const float4* zp = (const float4*)(Z2 + (size_t)b * 5120);
  const float4* bp = (const float4*)bias;
  float z[5][4];
#pragma unroll
  for (int ci = 0; ci < 5; ++ci) {
    float4 v = zp[ci * 256 + t];
    float4 bb = bp[ci * 256 + t];
    z[ci][0] = v.x + bb.x; z[ci][1] = v.y + bb.y;
    z[ci][2] = v.z + bb.z; z[ci][3] = v.w + bb.w;
  }
#pragma unroll
  for (int ci = 0; ci < 5; ++ci) {
    float s = z[ci][0] + z[ci][1] + z[ci][2] + z[ci][3];
    float mu = bsum<4>(s, shs) * (1.0f / 1024.0f);
    float ss = 0.f;
#pragma unroll
    for (int i = 0; i < 4; ++i) { float d = z[ci][i] - mu; ss += d * d; }
    float var = bsum<4>(ss, shs) * (1.0f / 1024.0f);
    float r = sqrtf(var + 1e-5f);
    float4 gv = ((const float4*)g1)[ci * 256 + t];
    float4 bv = ((const float4*)b1)[ci * 256 + t];
    z[ci][0] = (z[ci][0] - mu) / r * gv.x + bv.x;
    z[ci][1] = (z[ci][1] - mu) / r * gv.y + bv.y;
    z[ci][2] = (z[ci][2] - mu) / r * gv.z + bv.z;
    z[ci][3] = (z[ci][3] - mu) / r * gv.w + bv.w;
  }
  float4 cv = ((const float4*)(c + (size_t)b * 1024))[t];
  float cvv[4] = {cv.x, cv.y, cv.z, cv.w};
  float nc[4];
#pragma unroll
  for (int i = 0; i < 4; ++i)
    nc[i] = cvv[i] * sigm(z[2][i] + 1.0f) + sigm(z[0][i]) * tanhf(z[1][i]);
  float s = nc[0] + nc[1] + nc[2] + nc[3];
  float mu = bsum<4>(s, shs) * (1.0f / 1024.0f);
  float ss = 0.f;
#pragma unroll
  for (int i = 0; i < 4; ++i) { float d = nc[i] - mu; ss += d * d; }
  float var = bsum<4>(ss, shs) * (1.0f / 1024.0f);
  float r2 = sqrtf(var + 1e-5f);
  float4 g2v = ((const float4*)g2)[t];
  float4 b2v = ((const float4*)b2)[t];
  float g2a[4] = {g2v.x, g2v.y, g2v.z, g2v.w};
  float b2a[4] = {b2v.x, b2v.y, b2v.z, b2v.w};
  float4 hv = ((const float4*)(he + (size_t)b * 1024))[t];
  float hva[4] = {hv.x, hv.y, hv.z, hv.w};
  float4 o1, o2;
  float nh[4], rr[4];
#pragma unroll
  for (int i = 0; i < 4; ++i) {
    float ncn = (nc[i] - mu) / r2 * g2a[i] + b2a[i];
    nh[i] = tanhf(ncn) * sigm(z[3][i]);
    rr[i] = tanhf(hva[i]) * sigm(z[4][i]);
  }
  o1.x = nh[0]; o1.y = nh[1]; o1.z = nh[2]; o1.w = nh[3];
  o2.x = rr[0]; o2.y = rr[1]; o2.z = rr[2]; o2.w = rr[3];
  ((float4*)(out + (size_t)b * 2048))[t] = o1;
  ((float4*)(out + (size_t)b * 2048 + 1024))[t] = o2;
}

// ---------- launch ----------
extern "C" void kernel_launch(void* const* d_in, const int* in_sizes, int n_in,
                              void* d_out, int out_size, void* d_ws, size_t ws_size,
                              hipStream_t stream) {
  const float* x = (const float*)d_in[0];
  const float* c = (const float*)d_in[1];
  const float* hmem = (const float*)d_in[2];
  const float* ut = (const float*)d_in[3];
  const float* prev = (const float*)d_in[4];
  const float* gu = (const float*)d_in[5];
  const float* keys = (const float*)d_in[6];
  const float* veca = (const float*)d_in[7];
  const float* fcw = (const float*)d_in[8];
  const float* fcb = (const float*)d_in[9];
  const float* Wf = (const float*)d_in[10];
  const float* bias = (const float*)d_in[11];
  const float* Wf1 = (const float*)d_in[12];
  const float* bias1 = (const float*)d_in[13];
  const float* ln1g = (const float*)d_in[14];
  const float* ln1b = (const float*)d_in[15];
  const float* ln2g = (const float*)d_in[16];
  const float* ln2b = (const float*)d_in[17];
  const float* ln3g = (const float*)d_in[18];
  const float* ln3b = (const float*)d_in[19];
  const float* ln4g = (const float*)d_in[20];
  const float* ln4b = (const float*)d_in[21];

  char* ws = (char*)d_ws;
  float* UN = (float*)(ws + 0);            // 128 KB
  float* A2 = (float*)(ws + 131072);       // 128 KB
  float* A1 = (float*)(ws + 262144);       // 256 KB
  u16* W3H = (u16*)(ws + 524288);          // 512 KB
  u16* W3L = (u16*)(ws + 1048576);         // 512 KB
  float* SP = (float*)(ws + 1572864);      // 512 KB
  float* WGT = (float*)(ws + 2097152);     // 128 KB
  float* HE = (float*)(ws + 2228224);      // 1 MB
  u16* AB1 = (u16*)(ws + 3276800);         // 1.25 MB
  u16* AB2 = (u16*)(ws + 4587520);         // 1.25 MB
  float* Z1 = (float*)(ws + 5898240);      // 2 MB
  float* Z2 = (float*)(ws + 7995392);      // 5 MB

  hipMemsetAsync(A1, 0, (size_t)256 * 256 * 4, stream);
  hipMemsetAsync(Z1, 0, (size_t)256 * 2048 * 4, stream);
  hipMemsetAsync(Z2, 0, (size_t)256 * 5120 * 4, stream);
  k_prep<<<416, 256, 0, stream>>>(fcw, keys, ut, fcb, W3H, W3L, A2, UN);
  k_a1<<<832, 256, 0, stream>>>(x, c, UN, fcw, A1);
  k2_score<<<256, 512, 0, stream>>>(hmem, W3H, W3L, A1, A2, veca, SP);
  k3_softmax<<<256, 128, 0, stream>>>(SP, prev, gu, ln4g, ln4b, WGT);
  k4_gather<<<256, 256, 0, stream>>>(WGT, hmem, x, c, HE, AB1);
  gemm_cell<<<32 * 8, 256, 0, stream>>>(AB1, Wf1, Z1, 2048, 32, 10);
  k5b<<<256, 256, 0, stream>>>(Z1, bias1, x, c, HE, ln3g, ln3b, AB2);
  gemm_cell<<<80 * 4, 256, 0, stream>>>(AB2, Wf, Z2, 5120, 80, 20);
  k5d<<<256, 256, 0, stream>>>(Z2, bias, c, HE, ln1g, ln1b, ln2g, ln2b, (float*)d_out);
}

// Round 3
// 441.357 us; speedup vs baseline: 1.3822x; 1.0186x over previous
//
#include <hip/hip_runtime.h>
#include <cstdint>
#include <cstddef>

typedef unsigned short u16;
typedef float floatx4 __attribute__((ext_vector_type(4)));
typedef __bf16 bf16x8 __attribute__((ext_vector_type(8)));
typedef unsigned short u16x8 __attribute__((ext_vector_type(8)));
typedef unsigned short u16x4 __attribute__((ext_vector_type(4)));

// ---------- helpers ----------
__device__ __forceinline__ u16 f2bf(float f) {
  unsigned u = __float_as_uint(f);
  unsigned r = u + 0x7FFFu + ((u >> 16) & 1u);   // RNE
  return (u16)(r >> 16);
}
__device__ __forceinline__ float bf2f(u16 h) {
  return __uint_as_float(((unsigned)h) << 16);
}
__device__ __forceinline__ void gl_lds16(const void* g, void* l) {
  __builtin_amdgcn_global_load_lds(
      (const __attribute__((address_space(1))) unsigned int*)g,
      (__attribute__((address_space(3))) unsigned int*)l, 16, 0, 0);
}
__device__ __forceinline__ float wsum(float v) {
#pragma unroll
  for (int m = 32; m > 0; m >>= 1) v += __shfl_xor(v, m, 64);
  return v;
}
__device__ __forceinline__ float wmaxr(float v) {
#pragma unroll
  for (int m = 32; m > 0; m >>= 1) v = fmaxf(v, __shfl_xor(v, m, 64));
  return v;
}
template <int NW>
__device__ __forceinline__ float bsum(float v, float* sh) {
  int lane = threadIdx.x & 63, wid = threadIdx.x >> 6;
  v = wsum(v);
  __syncthreads();
  if (lane == 0) sh[wid] = v;
  __syncthreads();
  float t = 0.f;
#pragma unroll
  for (int i = 0; i < NW; ++i) t += sh[i];
  return t;
}
template <int NW>
__device__ __forceinline__ float bmaxr(float v, float* sh) {
  int lane = threadIdx.x & 63, wid = threadIdx.x >> 6;
  v = wmaxr(v);
  __syncthreads();
  if (lane == 0) sh[wid] = v;
  __syncthreads();
  float t = sh[0];
#pragma unroll
  for (int i = 1; i < NW; ++i) t = fmaxf(t, sh[i]);
  return t;
}
__device__ __forceinline__ float sigm(float x) { return 1.0f / (1.0f + expf(-x)); }

// ---------- prep: W3 hi/lo swizzle-packed tiles, A2 = fc_b + keys@W2, u_norm ----------
// blocks 0..127: W3 split (ks = blk>>2, octet q = blk&3)
// blocks 128..255: A2 row m; 256..511: u_norm row b
__global__ __launch_bounds__(256) void k_prep(
    const float* __restrict__ fcw, const float* __restrict__ keys,
    const float* __restrict__ ut, const float* __restrict__ fcb,
    u16* __restrict__ W3H, u16* __restrict__ W3L,
    float* __restrict__ A2, float* __restrict__ UN) {
  __shared__ float kr[64];
  __shared__ float shs[4];
  int blk = blockIdx.x, t = threadIdx.x;
  if (blk < 128) {
    int ks = blk >> 2, q = blk & 3;
    int slot = q ^ ((t >> 1) & 3);    // XOR-swizzled octet slot (bank-conflict fix)
    u16x8 vh, vl;
#pragma unroll
    for (int e = 0; e < 8; ++e) {
      float f = fcw[(size_t)(1600 + ks * 32 + q * 8 + e) * 256 + t];
      u16 h = f2bf(f);
      vh[e] = h;
      vl[e] = f2bf(f - bf2f(h));
    }
    *(u16x8*)&W3H[(size_t)ks * 8192 + t * 32 + slot * 8] = vh;
    *(u16x8*)&W3L[(size_t)ks * 8192 + t * 32 + slot * 8] = vl;
  } else if (blk < 256) {
    int m = blk - 128;
    if (t < 64) kr[t] = keys[m * 64 + t];
    __syncthreads();
    float acc = fcb[t];   // fold fc_b here (A1 is pure atomic accumulation)
#pragma unroll 8
    for (int j = 0; j < 64; ++j)
      acc = fmaf(kr[j], fcw[(size_t)(1536 + j) * 256 + t], acc);
    A2[m * 256 + t] = acc;
  } else {
    int b = blk - 256;
    float v = (t < 128) ? ut[b * 128 + t] : 0.f;
    float s = bsum<4>(v * v, shs);
    float dnm = fmaxf(sqrtf(s), 1e-12f);
    if (t < 128) UN[b * 128 + t] = v / dnm;
  }
}

// ---------- A1[b,k] += xc_un[b]@W1/W4 : split-K f32, atomic epilogue ----------
__global__ __launch_bounds__(256) void k_a1(
    const float* __restrict__ x, const float* __restrict__ c,
    const float* __restrict__ un, const float* __restrict__ fcw,
    float* __restrict__ A1) {
  __shared__ float sh[512];
  int kc = blockIdx.x % 26;
  int bg = blockIdx.x / 26;
  int t = threadIdx.x;
  int g0 = kc * 64;
  int row_base = (g0 < 1536) ? g0 : g0 + 1088;  // skip keys(64)+hmem(1024) rows
#pragma unroll
  for (int p = 0; p < 2; ++p) {
    int idx = p * 256 + t;
    int bl = idx >> 6, j = idx & 63;
    int b = bg * 8 + bl;
    int g = g0 + j;
    float v;
    if (g < 512) v = x[b * 512 + g];
    else if (g < 1536) v = c[b * 1024 + (g - 512)];
    else v = un[b * 128 + (g - 1536)];
    sh[idx] = v;
  }
  __syncthreads();
  float acc[8];
#pragma unroll
  for (int i = 0; i < 8; ++i) acc[i] = 0.f;
#pragma unroll 4
  for (int j = 0; j < 64; ++j) {
    float wv = fcw[(size_t)(row_base + j) * 256 + t];
#pragma unroll
    for (int bl = 0; bl < 8; ++bl)
      acc[bl] = fmaf(sh[bl * 64 + j], wv, acc[bl]);
  }
#pragma unroll
  for (int bl = 0; bl < 8; ++bl)
    atomicAdd(&A1[(bg * 8 + bl) * 256 + t], acc[bl]);
}

// ---------- K2: score GEMM — swizzled LDS, double-buffered, 1 barrier/step ----------
// grid 256 (one block per b), 512 threads. Block tile 128(m) x 256(hidden),
// wave tile 64x64; K=1024 in 32 steps; 3-pass split-bf16 (hh + hl + lh).
__global__ __launch_bounds__(512, 2) void k2_score(
    const float* __restrict__ hmem, const u16* __restrict__ Bhp,
    const u16* __restrict__ Blp, const float* __restrict__ A1,
    const float* __restrict__ A2, const float* __restrict__ va,
    float* __restrict__ sp) {
  __shared__ __align__(16) u16 Ah[2][4096];
  __shared__ __align__(16) u16 Al[2][4096];
  __shared__ __align__(16) u16 Bh[2][8192];
  __shared__ __align__(16) u16 Bl[2][8192];
  const int b = blockIdx.x;
  const int t = threadIdx.x;
  const int lane = t & 63, w = t >> 6;
  const int q = lane >> 4, r16 = lane & 15;
  const int rh = w >> 2, cq = w & 3;
  const int slot = q ^ ((r16 >> 1) & 3);   // frag-read octet slot (2-way max)

  floatx4 acc[4][4];
#pragma unroll
  for (int i = 0; i < 4; ++i)
#pragma unroll
    for (int j = 0; j < 4; ++j) acc[i][j] = (floatx4){0.f, 0.f, 0.f, 0.f};

  // A staging: thread (m_st, qh) owns octet qh of row m_st
  const int m_st = t >> 2, qh = t & 3;
  const int wslot = qh ^ ((m_st >> 1) & 3);
  const int aw_idx = m_st * 32 + wslot * 8;
  const float* aptr = hmem + ((size_t)(b * 128 + m_st)) * 1024 + qh * 8;

  // constant frag-read offsets (u16 units)
  int aoff[4], boff[4];
#pragma unroll
  for (int i = 0; i < 4; ++i) {
    int row = rh * 64 + i * 16 + r16;
    aoff[i] = row * 32 + slot * 8;
  }
#pragma unroll
  for (int ct = 0; ct < 4; ++ct) {
    int col = cq * 64 + ct * 16 + r16;
    boff[ct] = col * 32 + slot * 8;
  }

  // ---- prologue ----
  // DMA B step 0 into buf 0
#pragma unroll
  for (int i = 0; i < 2; ++i) {
    int L = (w * 2 + i) * 1024 + lane * 16;
    gl_lds16((const char*)Bhp + L, (char*)&Bh[0][0] + L);
    gl_lds16((const char*)Blp + L, (char*)&Bl[0][0] + L);
  }
  float pv[8];
#pragma unroll
  for (int i = 0; i < 8; ++i) pv[i] = aptr[i];        // A step 0
  {
    u16x8 hh, ll;
#pragma unroll
    for (int i = 0; i < 8; ++i) {
      u16 h = f2bf(pv[i]);
      hh[i] = h;
      ll[i] = f2bf(pv[i] - bf2f(h));
    }
    *(u16x8*)&Ah[0][aw_idx] = hh;
    *(u16x8*)&Al[0][aw_idx] = ll;
  }
#pragma unroll
  for (int i = 0; i < 8; ++i) pv[i] = aptr[32 + i];   // A step 1

  // ---- main loop: one barrier per step ----
  for (int ks = 0; ks < 32; ++ks) {
    const int cur = ks & 1, nxt = cur ^ 1;
    __syncthreads();   // writes (DMA + A) into cur complete; prev reads of nxt done
    if (ks < 31) {
#pragma unroll
      for (int i = 0; i < 2; ++i) {
        int L = (w * 2 + i) * 1024 + lane * 16;
        gl_lds16((const char*)Bhp + (size_t)(ks + 1) * 16384 + L, (char*)&Bh[nxt][0] + L);
        gl_lds16((const char*)Blp + (size_t)(ks + 1) * 16384 + L, (char*)&Bl[nxt][0] + L);
      }
      u16x8 hh, ll;
#pragma unroll
      for (int i = 0; i < 8; ++i) {
        u16 h = f2bf(pv[i]);
        hh[i] = h;
        ll[i] = f2bf(pv[i] - bf2f(h));
      }
      *(u16x8*)&Ah[nxt][aw_idx] = hh;
      *(u16x8*)&Al[nxt][aw_idx] = ll;
      if (ks < 30) {
        const float* np = aptr + (ks + 2) * 32;
#pragma unroll
        for (int i = 0; i < 8; ++i) pv[i] = np[i];
      }
    }
    bf16x8 ah[4], al[4];
#pragma unroll
    for (int i = 0; i < 4; ++i) {
      ah[i] = __builtin_bit_cast(bf16x8, *(const u16x8*)&Ah[cur][aoff[i]]);
      al[i] = __builtin_bit_cast(bf16x8, *(const u16x8*)&Al[cur][aoff[i]]);
    }
#pragma unroll
    for (int ct = 0; ct < 4; ++ct) {
      bf16x8 bh = __builtin_bit_cast(bf16x8, *(const u16x8*)&Bh[cur][boff[ct]]);
      bf16x8 bl = __builtin_bit_cast(bf16x8, *(const u16x8*)&Bl[cur][boff[ct]]);
#pragma unroll
      for (int i = 0; i < 4; ++i) {
        acc[i][ct] = __builtin_amdgcn_mfma_f32_16x16x32_bf16(ah[i], bh, acc[i][ct], 0, 0, 0);
        acc[i][ct] = __builtin_amdgcn_mfma_f32_16x16x32_bf16(ah[i], bl, acc[i][ct], 0, 0, 0);
        acc[i][ct] = __builtin_amdgcn_mfma_f32_16x16x32_bf16(al[i], bh, acc[i][ct], 0, 0, 0);
      }
    }
  }
  // epilogue: pre = acc + A1[b,col] + A2[m,col]; score partial = sum_col tanh(pre)*va[col]
  float rs[4][4];
#pragma unroll
  for (int i = 0; i < 4; ++i)
#pragma unroll
    for (int r = 0; r < 4; ++r) rs[i][r] = 0.f;
#pragma unroll
  for (int ct = 0; ct < 4; ++ct) {
    int col = cq * 64 + ct * 16 + r16;
    float a1v = A1[b * 256 + col];
    float vav = va[col];
#pragma unroll
    for (int i = 0; i < 4; ++i) {
      int row0 = rh * 64 + i * 16 + q * 4;
#pragma unroll
      for (int r = 0; r < 4; ++r) {
        float pre = acc[i][ct][r] + a1v + A2[(row0 + r) * 256 + col];
        rs[i][r] += tanhf(pre) * vav;
      }
    }
  }
#pragma unroll
  for (int mask = 1; mask <= 8; mask <<= 1)
#pragma unroll
    for (int i = 0; i < 4; ++i)
#pragma unroll
      for (int r = 0; r < 4; ++r) rs[i][r] += __shfl_xor(rs[i][r], mask, 64);
  if (r16 == 0) {
#pragma unroll
    for (int i = 0; i < 4; ++i)
#pragma unroll
      for (int r = 0; r < 4; ++r) {
        int row = rh * 64 + i * 16 + q * 4 + r;
        sp[cq * 32768 + b * 128 + row] = rs[i][r];
      }
  }
}

// ---------- K3: -100*prev, LN over M, gumbel, softmax, hard weights ----------
__global__ __launch_bounds__(128) void k3_softmax(
    const float* __restrict__ sp, const float* __restrict__ prev,
    const float* __restrict__ gu, const float* __restrict__ g4,
    const float* __restrict__ b4, float* __restrict__ wgt) {
  __shared__ float shs[2];
  int b = blockIdx.x, m = threadIdx.x;
  int bm = b * 128 + m;
  float s = sp[bm] + sp[32768 + bm] + sp[65536 + bm] + sp[98304 + bm];
  s -= prev[bm] * 100.0f;
  float mu = bsum<2>(s, shs) * (1.0f / 128.0f);
  float d = s - mu;
  float var = bsum<2>(d * d, shs) * (1.0f / 128.0f);
  float sn = d / sqrtf(var + 1e-5f) * g4[m] + b4[m];
  float gv = -logf(1e-20f - logf(1e-20f + gu[bm]));
  float z = (sn + gv) * 1.0f;  // TAU = 1
  float zm = bmaxr<2>(z, shs);
  float e = expf(z - zm);
  float Zs = bsum<2>(e, shs);
  float y = e / Zs;
  float ym = bmaxr<2>(y, shs);
  float hard = (y == ym) ? 1.0f : 0.0f;
  wgt[bm] = (hard - y) + y;  // exactly 0 for non-selected rows
}

// ---------- K4: h_entry gather + build concat0 bf16 (AB1, octet-swizzled) ----------
__global__ __launch_bounds__(256) void k4_gather(
    const float* __restrict__ wgt, const float* __restrict__ hmem,
    const float* __restrict__ x, const float* __restrict__ c,
    float* __restrict__ he, u16* __restrict__ ab1) {
  __shared__ float wsw[128];
  int b = blockIdx.x, t = threadIdx.x;
  if (t < 128) wsw[t] = wgt[b * 128 + t];
  __syncthreads();
  float4 a;
  a.x = a.y = a.z = a.w = 0.f;
  for (int mm = 0; mm < 128; ++mm) {
    float wm = wsw[mm];
    if (wm != 0.0f) {
      float4 v = ((const float4*)(hmem + ((size_t)(b * 128 + mm)) * 1024))[t];
      a.x = fmaf(wm, v.x, a.x);
      a.y = fmaf(wm, v.y, a.y);
      a.z = fmaf(wm, v.z, a.z);
      a.w = fmaf(wm, v.w, a.w);
    }
  }
  ((float4*)(he + (size_t)b * 1024))[t] = a;
  const int sx = ((b >> 1) & 3) << 3;   // octet swizzle for gemm_cell A-tile
  u16* row = ab1 + (size_t)b * 2560;
  if (t < 128) {
    float4 xv = ((const float4*)(x + (size_t)b * 512))[t];
    u16x4 o = {f2bf(xv.x), f2bf(xv.y), f2bf(xv.z), f2bf(xv.w)};
    *(u16x4*)&row[(t * 4) ^ sx] = o;
  }
  {
    float4 cv = ((const float4*)(c + (size_t)b * 1024))[t];
    u16x4 o = {f2bf(cv.x), f2bf(cv.y), f2bf(cv.z), f2bf(cv.w)};
    *(u16x4*)&row[(512 + t * 4) ^ sx] = o;
  }
  {
    u16x4 o = {f2bf(a.x), f2bf(a.y), f2bf(a.z), f2bf(a.w)};
    *(u16x4*)&row[(1536 + t * 4) ^ sx] = o;
  }
}

// ---------- cell GEMM: Z += Abf(bf16, swizzled) @ W(f32, converted in-kernel) ----------
__global__ __launch_bounds__(256) void gemm_cell(
    const u16* __restrict__ Abf, const float* __restrict__ W,
    float* __restrict__ Z, int N, int nblk, int nsteps) {
  __shared__ __align__(16) u16 Asm[256 * 32];
  __shared__ __align__(16) float Bf[32 * 64];
  __shared__ __align__(16) u16 Bsm[64 * 40];
  int cb = blockIdx.x % nblk;
  int kc = blockIdx.x / nblk;
  int t = threadIdx.x, lane = t & 63, w = t >> 6;
  int q = lane >> 4, r16 = lane & 15;
  const int axor = ((r16 >> 1) & 3) << 3;   // matches writer swizzle
  floatx4 acc[4][4];
#pragma unroll
  for (int i = 0; i < 4; ++i)
#pragma unroll
    for (int j = 0; j < 4; ++j) acc[i][j] = (floatx4){0.f, 0.f, 0.f, 0.f};
  int k0 = kc * nsteps * 32;
  for (int ks = 0; ks < nsteps; ++ks) {
    int k = k0 + ks * 32;
#pragma unroll
    for (int i = 0; i < 4; ++i) {
      int L = (w * 4 + i) * 1024 + lane * 16;
      int row = L >> 6, off = L & 63;
      gl_lds16((const char*)Abf + (size_t)row * 5120 + k * 2 + off, (char*)Asm + L);
    }
#pragma unroll
    for (int i = 0; i < 2; ++i) {
      int L = (w * 2 + i) * 1024 + lane * 16;
      int kr = L >> 8, off = L & 255;
      gl_lds16((const char*)W + ((size_t)(k + kr) * N + cb * 64) * 4 + off, (char*)Bf + L);
    }
    __syncthreads();
    {
      int cc = t & 63, p = t >> 6;
      u16x8 hh;
#pragma unroll
      for (int i2 = 0; i2 < 8; ++i2) hh[i2] = f2bf(Bf[(p * 8 + i2) * 64 + cc]);
      *(u16x8*)&Bsm[cc * 40 + p * 8] = hh;
    }
    __syncthreads();
    bf16x8 af[4];
#pragma unroll
    for (int i = 0; i < 4; ++i) {
      int row = w * 64 + i * 16 + r16;
      af[i] = __builtin_bit_cast(bf16x8, *(const u16x8*)&Asm[(row * 32 + q * 8) ^ axor]);
    }
#pragma unroll
    for (int ct = 0; ct < 4; ++ct) {
      int col = ct * 16 + r16;
      bf16x8 bb = __builtin_bit_cast(bf16x8, *(const u16x8*)&Bsm[col * 40 + q * 8]);
#pragma unroll
      for (int i = 0; i < 4; ++i)
        acc[i][ct] = __builtin_amdgcn_mfma_f32_16x16x32_bf16(af[i], bb, acc[i][ct], 0, 0, 0);
    }
    __syncthreads();
  }
#pragma unroll
  for (int ct = 0; ct < 4; ++ct)
#pragma unroll
    for (int i = 0; i < 4; ++i)
#pragma unroll
      for (int r = 0; r < 4; ++r) {
        int col = cb * 64 + ct * 16 + r16;
        int row = w * 64 + i * 16 + q * 4 + r;
        atomicAdd(&Z[(size_t)row * N + col], acc[i][ct][r]);
      }
}

// ---------- K5b: LN3(2 chunks)+sigmoid gate, build gated AB2 (swizzled) ----------
__global__ __launch_bounds__(256) void k5b(
    const float* __restrict__ Z1, const float* __restrict__ bias1,
    const float* __restrict__ x, const float* __restrict__ c,
    const float* __restrict__ he, const float* __restrict__ g3,
    const float* __restrict__ b3, u16* __restrict__ ab2) {
  __shared__ float shs[4];
  int b = blockIdx.x, t = threadIdx.x;
  const float4* zp = (const float4*)(Z1 + (size_t)b * 2048);
  const float4* bp = (const float4*)bias1;
  float4 z0v = zp[t], z1v = zp[256 + t];
  float4 q0 = bp[t], q1 = bp[256 + t];
  float za[4] = {z0v.x + q0.x, z0v.y + q0.y, z0v.z + q0.z, z0v.w + q0.w};
  float zb[4] = {z1v.x + q1.x, z1v.y + q1.y, z1v.z + q1.z, z1v.w + q1.w};
  float g1a[4], g1b[4];
  {
    float s = za[0] + za[1] + za[2] + za[3];
    float mu = bsum<4>(s, shs) * (1.0f / 1024.0f);
    float ss = 0.f;
#pragma unroll
    for (int i = 0; i < 4; ++i) { float d = za[i] - mu; ss += d * d; }
    float var = bsum<4>(ss, shs) * (1.0f / 1024.0f);
    float r = sqrtf(var + 1e-5f);
    float4 gv = ((const float4*)g3)[t];
    float4 bv = ((const float4*)b3)[t];
    g1a[0] = sigm((za[0] - mu) / r * gv.x + bv.x);
    g1a[1] = sigm((za[1] - mu) / r * gv.y + bv.y);
    g1a[2] = sigm((za[2] - mu) / r * gv.z + bv.z);
    g1a[3] = sigm((za[3] - mu) / r * gv.w + bv.w);
  }
  {
    float s = zb[0] + zb[1] + zb[2] + zb[3];
    float mu = bsum<4>(s, shs) * (1.0f / 1024.0f);
    float ss = 0.f;
#pragma unroll
    for (int i = 0; i < 4; ++i) { float d = zb[i] - mu; ss += d * d; }
    float var = bsum<4>(ss, shs) * (1.0f / 1024.0f);
    float r = sqrtf(var + 1e-5f);
    float4 gv = ((const float4*)g3)[256 + t];
    float4 bv = ((const float4*)b3)[256 + t];
    g1b[0] = sigm((zb[0] - mu) / r * gv.x + bv.x);
    g1b[1] = sigm((zb[1] - mu) / r * gv.y + bv.y);
    g1b[2] = sigm((zb[2] - mu) / r * gv.z + bv.z);
    g1b[3] = sigm((zb[3] - mu) / r * gv.w + bv.w);
  }
  const int sx = ((b >> 1) & 3) << 3;
  u16* row = ab2 + (size_t)b * 2560;
  if (t < 128) {
    float4 xv = ((const float4*)(x + (size_t)b * 512))[t];
    u16x4 o = {f2bf(xv.x), f2bf(xv.y), f2bf(xv.z), f2bf(xv.w)};
    *(u16x4*)&row[(t * 4) ^ sx] = o;
  }
  {
    float4 cv = ((const float4*)(c + (size_t)b * 1024))[t];
    u16x4 o = {f2bf(cv.x * g1a[0]), f2bf(cv.y * g1a[1]), f2bf(cv.z * g1a[2]), f2bf(cv.w * g1a[3])};
    *(u16x4*)&row[(512 + t * 4) ^ sx] = o;
  }
  {
    float4 hv = ((const float4*)(he + (size_t)b * 1024))[t];
    u16x4 o = {f2bf(hv.x * g1b[0]), f2bf(hv.y * g1b[1]), f2bf(hv.z * g1b[2]), f2bf(hv.w * g1b[3])};
    *(u16x4*)&row[(1536 + t * 4) ^ sx] = o;
  }
}

// ---------- K5d: LN1(5 chunks), cell update, LN2, outputs ----------
__global__ __launch_bounds__(256) void k5d(
    const float* __restrict__ Z2, const float* __restrict__ bias,
    const float* __restrict__ c, const float* __restrict__ he,
    const float* __restrict__ g1, const float* __restrict__ b1,
    const float* __restrict__ g2, const float* __restrict__ b2,
    float* __restrict__ out) {
  __shared__ float shs[4];
  int b = blockIdx.x, t = threadIdx.x;
  const float4* zp = (const float4*)(Z2 + (size_t)b * 5120);
  const float4* bp = (const float4*)bias;
  float z[5][4];
#pragma unroll
  for (int ci = 0; ci < 5; ++ci) {
    float4 v = zp[ci * 256 + t];
    float4 bb = bp[ci * 256 + t];
    z[ci][0] = v.x + bb.x; z[ci][1] = v.y + bb.y;
    z[ci][2] = v.z + bb.z; z[ci][3] = v.w + bb.w;
  }
#pragma unroll
  for (int ci = 0; ci < 5; ++ci) {
    float s = z[ci][0] + z[ci][1] + z[ci][2] + z[ci][3];
    float mu = bsum<4>(s, shs) * (1.0f / 1024.0f);
    float ss = 0.f;
#pragma unroll
    for (int i = 0; i < 4; ++i) { float d = z[ci][i] - mu; ss += d * d; }
    float var = bsum<4>(ss, shs) * (1.0f / 1024.0f);
    float r = sqrtf(var + 1e-5f);
    float4 gv = ((const float4*)g1)[ci * 256 + t];
    float4 bv = ((const float4*)b1)[ci * 256 + t];
    z[ci][0] = (z[ci][0] - mu) / r * gv.x + bv.x;
    z[ci][1] = (z[ci][1] - mu) / r * gv.y + bv.y;
    z[ci][2] = (z[ci][2] - mu) / r * gv.z + bv.z;
    z[ci][3] = (z[ci][3] - mu) / r * gv.w + bv.w;
  }
  float4 cv = ((const float4*)(c + (size_t)b * 1024))[t];
  float cvv[4] = {cv.x, cv.y, cv.z, cv.w};
  float nc[4];
#pragma unroll
  for (int i = 0; i < 4; ++i)
    nc[i] = cvv[i] * sigm(z[2][i] + 1.0f) + sigm(z[0][i]) * tanhf(z[1][i]);
  float s = nc[0] + nc[1] + nc[2] + nc[3];
  float mu = bsum<4>(s, shs) * (1.0f / 1024.0f);
  float ss = 0.f;
#pragma unroll
  for (int i = 0; i < 4; ++i) { float d = nc[i] - mu; ss += d * d; }
  float var = bsum<4>(ss, shs) * (1.0f / 1024.0f);
  float r2 = sqrtf(var + 1e-5f);
  float4 g2v = ((const float4*)g2)[t];
  float4 b2v = ((const float4*)b2)[t];
  float g2a[4] = {g2v.x, g2v.y, g2v.z, g2v.w};
  float b2a[4] = {b2v.x, b2v.y, b2v.z, b2v.w};
  float4 hv = ((const float4*)(he + (size_t)b * 1024))[t];
  float hva[4] = {hv.x, hv.y, hv.z, hv.w};
  float4 o1, o2;
  float nh[4], rr[4];
#pragma unroll
  for (int i = 0; i < 4; ++i) {
    float ncn = (nc[i] - mu) / r2 * g2a[i] + b2a[i];
    nh[i] = tanhf(ncn) * sigm(z[3][i]);
    rr[i] = tanhf(hva[i]) * sigm(z[4][i]);
  }
  o1.x = nh[0]; o1.y = nh[1]; o1.z = nh[2]; o1.w = nh[3];
  o2.x = rr[0]; o2.y = rr[1]; o2.z = rr[2]; o2.w = rr[3];
  ((float4*)(out + (size_t)b * 2048))[t] = o1;
  ((float4*)(out + (size_t)b * 2048 + 1024))[t] = o2;
}

// ---------- launch ----------
extern "C" void kernel_launch(void* const* d_in, const int* in_sizes, int n_in,
                              void* d_out, int out_size, void* d_ws, size_t ws_size,
                              hipStream_t stream) {
  const float* x = (const float*)d_in[0];
  const float* c = (const float*)d_in[1];
  const float* hmem = (const float*)d_in[2];
  const float* ut = (const float*)d_in[3];
  const float* prev = (const float*)d_in[4];
  const float* gu = (const float*)d_in[5];
  const float* keys = (const float*)d_in[6];
  const float* veca = (const float*)d_in[7];
  const float* fcw = (const float*)d_in[8];
  const float* fcb = (const float*)d_in[9];
  const float* Wf = (const float*)d_in[10];
  const float* bias = (const float*)d_in[11];
  const float* Wf1 = (const float*)d_in[12];
  const float* bias1 = (const float*)d_in[13];
  const float* ln1g = (const float*)d_in[14];
  const float* ln1b = (const float*)d_in[15];
  const float* ln2g = (const float*)d_in[16];
  const float* ln2b = (const float*)d_in[17];
  const float* ln3g = (const float*)d_in[18];
  const float* ln3b = (const float*)d_in[19];
  const float* ln4g = (const float*)d_in[20];
  const float* ln4b = (const float*)d_in[21];

  char* ws = (char*)d_ws;
  float* UN = (float*)(ws + 0);            // 128 KB
  float* A2 = (float*)(ws + 131072);       // 128 KB
  float* A1 = (float*)(ws + 262144);       // 256 KB
  u16* W3H = (u16*)(ws + 524288);          // 512 KB
  u16* W3L = (u16*)(ws + 1048576);         // 512 KB
  float* SP = (float*)(ws + 1572864);      // 512 KB
  float* WGT = (float*)(ws + 2097152);     // 128 KB
  float* HE = (float*)(ws + 2228224);      // 1 MB
  u16* AB1 = (u16*)(ws + 3276800);         // 1.25 MB
  u16* AB2 = (u16*)(ws + 4587520);         // 1.25 MB
  float* Z1 = (float*)(ws + 5898240);      // 2 MB
  float* Z2 = (float*)(ws + 7995392);      // 5 MB

  hipMemsetAsync(A1, 0, (size_t)256 * 256 * 4, stream);
  hipMemsetAsync(Z1, 0, (size_t)256 * 2048 * 4, stream);
  hipMemsetAsync(Z2, 0, (size_t)256 * 5120 * 4, stream);
  k_prep<<<512, 256, 0, stream>>>(fcw, keys, ut, fcb, W3H, W3L, A2, UN);
  k_a1<<<832, 256, 0, stream>>>(x, c, UN, fcw, A1);
  k2_score<<<256, 512, 0, stream>>>(hmem, W3H, W3L, A1, A2, veca, SP);
  k3_softmax<<<256, 128, 0, stream>>>(SP, prev, gu, ln4g, ln4b, WGT);
  k4_gather<<<256, 256, 0, stream>>>(WGT, hmem, x, c, HE, AB1);
  gemm_cell<<<32 * 8, 256, 0, stream>>>(AB1, Wf1, Z1, 2048, 32, 10);
  k5b<<<256, 256, 0, stream>>>(Z1, bias1, x, c, HE, ln3g, ln3b, AB2);
  gemm_cell<<<80 * 4, 256, 0, stream>>>(AB2, Wf, Z2, 5120, 80, 20);
  k5d<<<256, 256, 0, stream>>>(Z2, bias, c, HE, ln1g, ln1b, ln2g, ln2b, (float*)d_out);
}

// Round 4
// 426.494 us; speedup vs baseline: 1.4304x; 1.0349x over previous
//
#include <hip/hip_runtime.h>
#include <cstdint>
#include <cstddef>

typedef unsigned short u16;
typedef float floatx4 __attribute__((ext_vector_type(4)));
typedef __bf16 bf16x8 __attribute__((ext_vector_type(8)));
typedef unsigned short u16x8 __attribute__((ext_vector_type(8)));
typedef unsigned short u16x4 __attribute__((ext_vector_type(4)));

// ---------- helpers ----------
__device__ __forceinline__ u16 f2bf(float f) {
  unsigned u = __float_as_uint(f);
  unsigned r = u + 0x7FFFu + ((u >> 16) & 1u);   // RNE
  return (u16)(r >> 16);
}
__device__ __forceinline__ float bf2f(u16 h) {
  return __uint_as_float(((unsigned)h) << 16);
}
__device__ __forceinline__ void gl_lds16(const void* g, void* l) {
  __builtin_amdgcn_global_load_lds(
      (const __attribute__((address_space(1))) unsigned int*)g,
      (__attribute__((address_space(3))) unsigned int*)l, 16, 0, 0);
}
__device__ __forceinline__ float wsum(float v) {
#pragma unroll
  for (int m = 32; m > 0; m >>= 1) v += __shfl_xor(v, m, 64);
  return v;
}
__device__ __forceinline__ float wmaxr(float v) {
#pragma unroll
  for (int m = 32; m > 0; m >>= 1) v = fmaxf(v, __shfl_xor(v, m, 64));
  return v;
}
template <int NW>
__device__ __forceinline__ float bsum(float v, float* sh) {
  int lane = threadIdx.x & 63, wid = threadIdx.x >> 6;
  v = wsum(v);
  __syncthreads();
  if (lane == 0) sh[wid] = v;
  __syncthreads();
  float t = 0.f;
#pragma unroll
  for (int i = 0; i < NW; ++i) t += sh[i];
  return t;
}
template <int NW>
__device__ __forceinline__ float bmaxr(float v, float* sh) {
  int lane = threadIdx.x & 63, wid = threadIdx.x >> 6;
  v = wmaxr(v);
  __syncthreads();
  if (lane == 0) sh[wid] = v;
  __syncthreads();
  float t = sh[0];
#pragma unroll
  for (int i = 1; i < NW; ++i) t = fmaxf(t, sh[i]);
  return t;
}
__device__ __forceinline__ float sigm(float x) { return 1.0f / (1.0f + expf(-x)); }

// ---------- prep: W3 hi/lo swizzle-packed tiles, A2 = fc_b + keys@W2, u_norm ----------
__global__ __launch_bounds__(256) void k_prep(
    const float* __restrict__ fcw, const float* __restrict__ keys,
    const float* __restrict__ ut, const float* __restrict__ fcb,
    u16* __restrict__ W3H, u16* __restrict__ W3L,
    float* __restrict__ A2, float* __restrict__ UN) {
  __shared__ float kr[64];
  __shared__ float shs[4];
  int blk = blockIdx.x, t = threadIdx.x;
  if (blk < 128) {
    int ks = blk >> 2, q = blk & 3;
    int slot = q ^ ((t >> 1) & 3);    // XOR-swizzled octet slot
    u16x8 vh, vl;
#pragma unroll
    for (int e = 0; e < 8; ++e) {
      float f = fcw[(size_t)(1600 + ks * 32 + q * 8 + e) * 256 + t];
      u16 h = f2bf(f);
      vh[e] = h;
      vl[e] = f2bf(f - bf2f(h));
    }
    *(u16x8*)&W3H[(size_t)ks * 8192 + t * 32 + slot * 8] = vh;
    *(u16x8*)&W3L[(size_t)ks * 8192 + t * 32 + slot * 8] = vl;
  } else if (blk < 256) {
    int m = blk - 128;
    if (t < 64) kr[t] = keys[m * 64 + t];
    __syncthreads();
    float acc = fcb[t];
#pragma unroll 8
    for (int j = 0; j < 64; ++j)
      acc = fmaf(kr[j], fcw[(size_t)(1536 + j) * 256 + t], acc);
    A2[m * 256 + t] = acc;
  } else {
    int b = blk - 256;
    float v = (t < 128) ? ut[b * 128 + t] : 0.f;
    float s = bsum<4>(v * v, shs);
    float dnm = fmaxf(sqrtf(s), 1e-12f);
    if (t < 128) UN[b * 128 + t] = v / dnm;
  }
}

// ---------- A1[b,k] += xc_un[b]@W1/W4 : split-K f32, atomic epilogue ----------
__global__ __launch_bounds__(256) void k_a1(
    const float* __restrict__ x, const float* __restrict__ c,
    const float* __restrict__ un, const float* __restrict__ fcw,
    float* __restrict__ A1) {
  __shared__ float sh[512];
  int kc = blockIdx.x % 26;
  int bg = blockIdx.x / 26;
  int t = threadIdx.x;
  int g0 = kc * 64;
  int row_base = (g0 < 1536) ? g0 : g0 + 1088;
#pragma unroll
  for (int p = 0; p < 2; ++p) {
    int idx = p * 256 + t;
    int bl = idx >> 6, j = idx & 63;
    int b = bg * 8 + bl;
    int g = g0 + j;
    float v;
    if (g < 512) v = x[b * 512 + g];
    else if (g < 1536) v = c[b * 1024 + (g - 512)];
    else v = un[b * 128 + (g - 1536)];
    sh[idx] = v;
  }
  __syncthreads();
  float acc[8];
#pragma unroll
  for (int i = 0; i < 8; ++i) acc[i] = 0.f;
#pragma unroll 4
  for (int j = 0; j < 64; ++j) {
    float wv = fcw[(size_t)(row_base + j) * 256 + t];
#pragma unroll
    for (int bl = 0; bl < 8; ++bl)
      acc[bl] = fmaf(sh[bl * 64 + j], wv, acc[bl]);
  }
#pragma unroll
  for (int bl = 0; bl < 8; ++bl)
    atomicAdd(&A1[(bg * 8 + bl) * 256 + t], acc[bl]);
}

// ---------- K2: score GEMM — row-split (64x256 tile), 2 blocks/CU, dbuf ----------
// grid 512 = (b, half). 256 threads = 4 waves (col quarters). K=1024, 32 steps,
// 3-pass split-bf16. LDS 80KB -> exactly 2 blocks/CU.
__global__ __launch_bounds__(256, 2) void k2_score(
    const float* __restrict__ hmem, const u16* __restrict__ Bhp,
    const u16* __restrict__ Blp, const float* __restrict__ A1,
    const float* __restrict__ A2, const float* __restrict__ va,
    float* __restrict__ sp) {
  __shared__ __align__(16) u16 Ah[2][2048];
  __shared__ __align__(16) u16 Al[2][2048];
  __shared__ __align__(16) u16 Bh[2][8192];
  __shared__ __align__(16) u16 Bl[2][8192];
  const int b = blockIdx.x >> 1, hf = blockIdx.x & 1;
  const int t = threadIdx.x;
  const int lane = t & 63, w = t >> 6;   // w = col quarter cq
  const int q = lane >> 4, r16 = lane & 15;
  const int cq = w;
  const int slot = q ^ ((r16 >> 1) & 3);

  floatx4 acc[4][4];
#pragma unroll
  for (int i = 0; i < 4; ++i)
#pragma unroll
    for (int j = 0; j < 4; ++j) acc[i][j] = (floatx4){0.f, 0.f, 0.f, 0.f};

  // A staging: thread (m_st 0..63, qh 0..3)
  const int m_st = t >> 2, qh = t & 3;
  const int wslot = qh ^ ((m_st >> 1) & 3);
  const int aw_idx = m_st * 32 + wslot * 8;
  const float* aptr = hmem + ((size_t)(b * 128 + hf * 64 + m_st)) * 1024 + qh * 8;

  int aoff[4], boff[4];
#pragma unroll
  for (int i = 0; i < 4; ++i) aoff[i] = (i * 16 + r16) * 32 + slot * 8;
#pragma unroll
  for (int ct = 0; ct < 4; ++ct) boff[ct] = (cq * 64 + ct * 16 + r16) * 32 + slot * 8;

  // ---- prologue ----
#pragma unroll
  for (int i = 0; i < 4; ++i) {
    int L = (w * 4 + i) * 1024 + lane * 16;
    gl_lds16((const char*)Bhp + L, (char*)&Bh[0][0] + L);
    gl_lds16((const char*)Blp + L, (char*)&Bl[0][0] + L);
  }
  float pv[8];
#pragma unroll
  for (int i = 0; i < 8; ++i) pv[i] = aptr[i];
  {
    u16x8 hh, ll;
#pragma unroll
    for (int i = 0; i < 8; ++i) {
      u16 h = f2bf(pv[i]);
      hh[i] = h;
      ll[i] = f2bf(pv[i] - bf2f(h));
    }
    *(u16x8*)&Ah[0][aw_idx] = hh;
    *(u16x8*)&Al[0][aw_idx] = ll;
  }
#pragma unroll
  for (int i = 0; i < 8; ++i) pv[i] = aptr[32 + i];

  // ---- main loop: one barrier per step ----
  for (int ks = 0; ks < 32; ++ks) {
    const int cur = ks & 1, nxt = cur ^ 1;
    __syncthreads();
    if (ks < 31) {
#pragma unroll
      for (int i = 0; i < 4; ++i) {
        int L = (w * 4 + i) * 1024 + lane * 16;
        gl_lds16((const char*)Bhp + (size_t)(ks + 1) * 16384 + L, (char*)&Bh[nxt][0] + L);
        gl_lds16((const char*)Blp + (size_t)(ks + 1) * 16384 + L, (char*)&Bl[nxt][0] + L);
      }
      u16x8 hh, ll;
#pragma unroll
      for (int i = 0; i < 8; ++i) {
        u16 h = f2bf(pv[i]);
        hh[i] = h;
        ll[i] = f2bf(pv[i] - bf2f(h));
      }
      *(u16x8*)&Ah[nxt][aw_idx] = hh;
      *(u16x8*)&Al[nxt][aw_idx] = ll;
      if (ks < 30) {
        const float* np = aptr + (ks + 2) * 32;
#pragma unroll
        for (int i = 0; i < 8; ++i) pv[i] = np[i];
      }
    }
    bf16x8 ah[4], al[4];
#pragma unroll
    for (int i = 0; i < 4; ++i) {
      ah[i] = __builtin_bit_cast(bf16x8, *(const u16x8*)&Ah[cur][aoff[i]]);
      al[i] = __builtin_bit_cast(bf16x8, *(const u16x8*)&Al[cur][aoff[i]]);
    }
#pragma unroll
    for (int ct = 0; ct < 4; ++ct) {
      bf16x8 bh = __builtin_bit_cast(bf16x8, *(const u16x8*)&Bh[cur][boff[ct]]);
      bf16x8 bl = __builtin_bit_cast(bf16x8, *(const u16x8*)&Bl[cur][boff[ct]]);
#pragma unroll
      for (int i = 0; i < 4; ++i) {
        acc[i][ct] = __builtin_amdgcn_mfma_f32_16x16x32_bf16(ah[i], bh, acc[i][ct], 0, 0, 0);
        acc[i][ct] = __builtin_amdgcn_mfma_f32_16x16x32_bf16(ah[i], bl, acc[i][ct], 0, 0, 0);
        acc[i][ct] = __builtin_amdgcn_mfma_f32_16x16x32_bf16(al[i], bh, acc[i][ct], 0, 0, 0);
      }
    }
  }
  // epilogue
  float rs[4][4];
#pragma unroll
  for (int i = 0; i < 4; ++i)
#pragma unroll
    for (int r = 0; r < 4; ++r) rs[i][r] = 0.f;
#pragma unroll
  for (int ct = 0; ct < 4; ++ct) {
    int col = cq * 64 + ct * 16 + r16;
    float a1v = A1[b * 256 + col];
    float vav = va[col];
#pragma unroll
    for (int i = 0; i < 4; ++i) {
      int m0 = hf * 64 + i * 16 + q * 4;
#pragma unroll
      for (int r = 0; r < 4; ++r) {
        float pre = acc[i][ct][r] + a1v + A2[(m0 + r) * 256 + col];
        rs[i][r] += tanhf(pre) * vav;
      }
    }
  }
#pragma unroll
  for (int mask = 1; mask <= 8; mask <<= 1)
#pragma unroll
    for (int i = 0; i < 4; ++i)
#pragma unroll
      for (int r = 0; r < 4; ++r) rs[i][r] += __shfl_xor(rs[i][r], mask, 64);
  if (r16 == 0) {
#pragma unroll
    for (int i = 0; i < 4; ++i)
#pragma unroll
      for (int r = 0; r < 4; ++r) {
        int row = hf * 64 + i * 16 + q * 4 + r;
        sp[cq * 32768 + b * 128 + row] = rs[i][r];
      }
  }
}

// ---------- K34: softmax/hard-read (fused k3) + h_entry gather + AB1 build ----------
__global__ __launch_bounds__(256) void k34(
    const float* __restrict__ sp, const float* __restrict__ prev,
    const float* __restrict__ gu, const float* __restrict__ g4,
    const float* __restrict__ b4, const float* __restrict__ hmem,
    const float* __restrict__ x, const float* __restrict__ c,
    float* __restrict__ he, u16* __restrict__ ab1) {
  __shared__ float wsw[128];
  __shared__ float shs[4];
  int b = blockIdx.x, t = threadIdx.x;
  bool act = (t < 128);
  float s = 0.f;
  if (act) {
    int bm = b * 128 + t;
    s = sp[bm] + sp[32768 + bm] + sp[65536 + bm] + sp[98304 + bm] - prev[bm] * 100.0f;
  }
  float mu = bsum<4>(s, shs) * (1.0f / 128.0f);
  float d = act ? (s - mu) : 0.f;
  float var = bsum<4>(d * d, shs) * (1.0f / 128.0f);
  float z = -INFINITY;
  if (act) {
    float sn = d / sqrtf(var + 1e-5f) * g4[t] + b4[t];
    float gv = -logf(1e-20f - logf(1e-20f + gu[b * 128 + t]));
    z = sn + gv;   // TAU = 1
  }
  float zm = bmaxr<4>(z, shs);
  float e = act ? expf(z - zm) : 0.f;
  float Zs = bsum<4>(e, shs);
  float y = e / Zs;
  float ym = bmaxr<4>(y, shs);
  if (act) {
    float hard = (y == ym) ? 1.0f : 0.0f;
    wsw[t] = (hard - y) + y;   // exactly 0 for non-selected rows
  }
  __syncthreads();
  float4 a;
  a.x = a.y = a.z = a.w = 0.f;
  for (int mm = 0; mm < 128; ++mm) {
    float wm = wsw[mm];
    if (wm != 0.0f) {   // wave-uniform, ~1 of 128 taken
      float4 v = ((const float4*)(hmem + ((size_t)(b * 128 + mm)) * 1024))[t];
      a.x = fmaf(wm, v.x, a.x);
      a.y = fmaf(wm, v.y, a.y);
      a.z = fmaf(wm, v.z, a.z);
      a.w = fmaf(wm, v.w, a.w);
    }
  }
  ((float4*)(he + (size_t)b * 1024))[t] = a;
  const int sx = ((b >> 1) & 3) << 3;
  u16* row = ab1 + (size_t)b * 2560;
  if (t < 128) {
    float4 xv = ((const float4*)(x + (size_t)b * 512))[t];
    u16x4 o = {f2bf(xv.x), f2bf(xv.y), f2bf(xv.z), f2bf(xv.w)};
    *(u16x4*)&row[(t * 4) ^ sx] = o;
  }
  {
    float4 cv = ((const float4*)(c + (size_t)b * 1024))[t];
    u16x4 o = {f2bf(cv.x), f2bf(cv.y), f2bf(cv.z), f2bf(cv.w)};
    *(u16x4*)&row[(512 + t * 4) ^ sx] = o;
  }
  {
    u16x4 o = {f2bf(a.x), f2bf(a.y), f2bf(a.z), f2bf(a.w)};
    *(u16x4*)&row[(1536 + t * 4) ^ sx] = o;
  }
}

// ---------- cell GEMM: Zp[kc] = Abf(bf16, swizzled) @ W(f32) — plain stores ----------
__global__ __launch_bounds__(256) void gemm_cell(
    const u16* __restrict__ Abf, const float* __restrict__ W,
    float* __restrict__ Zp, int N, int nblk, int nsteps) {
  __shared__ __align__(16) u16 Asm[256 * 32];
  __shared__ __align__(16) float Bf[32 * 64];
  __shared__ __align__(16) u16 Bsm[64 * 40];
  int cb = blockIdx.x % nblk;
  int kc = blockIdx.x / nblk;
  int t = threadIdx.x, lane = t & 63, w = t >> 6;
  int q = lane >> 4, r16 = lane & 15;
  const int axor = ((r16 >> 1) & 3) << 3;
  floatx4 acc[4][4];
#pragma unroll
  for (int i = 0; i < 4; ++i)
#pragma unroll
    for (int j = 0; j < 4; ++j) acc[i][j] = (floatx4){0.f, 0.f, 0.f, 0.f};
  int k0 = kc * nsteps * 32;
  for (int ks = 0; ks < nsteps; ++ks) {
    int k = k0 + ks * 32;
#pragma unroll
    for (int i = 0; i < 4; ++i) {
      int L = (w * 4 + i) * 1024 + lane * 16;
      int row = L >> 6, off = L & 63;
      gl_lds16((const char*)Abf + (size_t)row * 5120 + k * 2 + off, (char*)Asm + L);
    }
#pragma unroll
    for (int i = 0; i < 2; ++i) {
      int L = (w * 2 + i) * 1024 + lane * 16;
      int kr = L >> 8, off = L & 255;
      gl_lds16((const char*)W + ((size_t)(k + kr) * N + cb * 64) * 4 + off, (char*)Bf + L);
    }
    __syncthreads();
    {
      int cc = t & 63, p = t >> 6;
      u16x8 hh;
#pragma unroll
      for (int i2 = 0; i2 < 8; ++i2) hh[i2] = f2bf(Bf[(p * 8 + i2) * 64 + cc]);
      *(u16x8*)&Bsm[cc * 40 + p * 8] = hh;
    }
    __syncthreads();
    bf16x8 af[4];
#pragma unroll
    for (int i = 0; i < 4; ++i) {
      int row = w * 64 + i * 16 + r16;
      af[i] = __builtin_bit_cast(bf16x8, *(const u16x8*)&Asm[(row * 32 + q * 8) ^ axor]);
    }
#pragma unroll
    for (int ct = 0; ct < 4; ++ct) {
      int col = ct * 16 + r16;
      bf16x8 bb = __builtin_bit_cast(bf16x8, *(const u16x8*)&Bsm[col * 40 + q * 8]);
#pragma unroll
      for (int i = 0; i < 4; ++i)
        acc[i][ct] = __builtin_amdgcn_mfma_f32_16x16x32_bf16(af[i], bb, acc[i][ct], 0, 0, 0);
    }
    __syncthreads();
  }
  float* dst = Zp + (size_t)kc * 256 * N;
#pragma unroll
  for (int ct = 0; ct < 4; ++ct)
#pragma unroll
    for (int i = 0; i < 4; ++i)
#pragma unroll
      for (int r = 0; r < 4; ++r) {
        int col = cb * 64 + ct * 16 + r16;
        int row = w * 64 + i * 16 + q * 4 + r;
        dst[(size_t)row * N + col] = acc[i][ct][r];
      }
}

// ---------- K5b: sum Z1 partials, LN3+sigmoid gate, build gated AB2 ----------
__global__ __launch_bounds__(256) void k5b(
    const float* __restrict__ Z1p, const float* __restrict__ bias1,
    const float* __restrict__ x, const float* __restrict__ c,
    const float* __restrict__ he, const float* __restrict__ g3,
    const float* __restrict__ b3, u16* __restrict__ ab2) {
  __shared__ float shs[4];
  int b = blockIdx.x, t = threadIdx.x;
  const float4* bp = (const float4*)bias1;
  float4 q0 = bp[t], q1 = bp[256 + t];
  float za[4] = {q0.x, q0.y, q0.z, q0.w};
  float zb[4] = {q1.x, q1.y, q1.z, q1.w};
#pragma unroll
  for (int kc = 0; kc < 8; ++kc) {
    const float4* zp = (const float4*)(Z1p + (size_t)kc * 524288 + (size_t)b * 2048);
    float4 v0 = zp[t], v1 = zp[256 + t];
    za[0] += v0.x; za[1] += v0.y; za[2] += v0.z; za[3] += v0.w;
    zb[0] += v1.x; zb[1] += v1.y; zb[2] += v1.z; zb[3] += v1.w;
  }
  float g1a[4], g1b[4];
  {
    float s = za[0] + za[1] + za[2] + za[3];
    float mu = bsum<4>(s, shs) * (1.0f / 1024.0f);
    float ss = 0.f;
#pragma unroll
    for (int i = 0; i < 4; ++i) { float d = za[i] - mu; ss += d * d; }
    float var = bsum<4>(ss, shs) * (1.0f / 1024.0f);
    float r = sqrtf(var + 1e-5f);
    float4 gv = ((const float4*)g3)[t];
    float4 bv = ((const float4*)b3)[t];
    g1a[0] = sigm((za[0] - mu) / r * gv.x + bv.x);
    g1a[1] = sigm((za[1] - mu) / r * gv.y + bv.y);
    g1a[2] = sigm((za[2] - mu) / r * gv.z + bv.z);
    g1a[3] = sigm((za[3] - mu) / r * gv.w + bv.w);
  }
  {
    float s = zb[0] + zb[1] + zb[2] + zb[3];
    float mu = bsum<4>(s, shs) * (1.0f / 1024.0f);
    float ss = 0.f;
#pragma unroll
    for (int i = 0; i < 4; ++i) { float d = zb[i] - mu; ss += d * d; }
    float var = bsum<4>(ss, shs) * (1.0f / 1024.0f);
    float r = sqrtf(var + 1e-5f);
    float4 gv = ((const float4*)g3)[256 + t];
    float4 bv = ((const float4*)b3)[256 + t];
    g1b[0] = sigm((zb[0] - mu) / r * gv.x + bv.x);
    g1b[1] = sigm((zb[1] - mu) / r * gv.y + bv.y);
    g1b[2] = sigm((zb[2] - mu) / r * gv.z + bv.z);
    g1b[3] = sigm((zb[3] - mu) / r * gv.w + bv.w);
  }
  const int sx = ((b >> 1) & 3) << 3;
  u16* row = ab2 + (size_t)b * 2560;
  if (t < 128) {
    float4 xv = ((const float4*)(x + (size_t)b * 512))[t];
    u16x4 o = {f2bf(xv.x), f2bf(xv.y), f2bf(xv.z), f2bf(xv.w)};
    *(u16x4*)&row[(t * 4) ^ sx] = o;
  }
  {
    float4 cv = ((const float4*)(c + (size_t)b * 1024))[t];
    u16x4 o = {f2bf(cv.x * g1a[0]), f2bf(cv.y * g1a[1]), f2bf(cv.z * g1a[2]), f2bf(cv.w * g1a[3])};
    *(u16x4*)&row[(512 + t * 4) ^ sx] = o;
  }
  {
    float4 hv = ((const float4*)(he + (size_t)b * 1024))[t];
    u16x4 o = {f2bf(hv.x * g1b[0]), f2bf(hv.y * g1b[1]), f2bf(hv.z * g1b[2]), f2bf(hv.w * g1b[3])};
    *(u16x4*)&row[(1536 + t * 4) ^ sx] = o;
  }
}

// ---------- K5d: sum Z2 partials, LN1(5), cell update, LN2, outputs ----------
__global__ __launch_bounds__(256) void k5d(
    const float* __restrict__ Z2p, const float* __restrict__ bias,
    const float* __restrict__ c, const float* __restrict__ he,
    const float* __restrict__ g1, const float* __restrict__ b1,
    const float* __restrict__ g2, const float* __restrict__ b2,
    float* __restrict__ out) {
  __shared__ float shs[4];
  int b = blockIdx.x, t = threadIdx.x;
  const float4* bp = (const float4*)bias;
  float z[5][4];
#pragma unroll
  for (int ci = 0; ci < 5; ++ci) {
    float4 bb = bp[ci * 256 + t];
    z[ci][0] = bb.x; z[ci][1] = bb.y; z[ci][2] = bb.z; z[ci][3] = bb.w;
  }
#pragma unroll
  for (int kc = 0; kc < 4; ++kc) {
    const float4* zp = (const float4*)(Z2p + (size_t)kc * 1310720 + (size_t)b * 5120);
#pragma unroll
    for (int ci = 0; ci < 5; ++ci) {
      float4 v = zp[ci * 256 + t];
      z[ci][0] += v.x; z[ci][1] += v.y; z[ci][2] += v.z; z[ci][3] += v.w;
    }
  }
#pragma unroll
  for (int ci = 0; ci < 5; ++ci) {
    float s = z[ci][0] + z[ci][1] + z[ci][2] + z[ci][3];
    float mu = bsum<4>(s, shs) * (1.0f / 1024.0f);
    float ss = 0.f;
#pragma unroll
    for (int i = 0; i < 4; ++i) { float d = z[ci][i] - mu; ss += d * d; }
    float var = bsum<4>(ss, shs) * (1.0f / 1024.0f);
    float r = sqrtf(var + 1e-5f);
    float4 gv = ((const float4*)g1)[ci * 256 + t];
    float4 bv = ((const float4*)b1)[ci * 256 + t];
    z[ci][0] = (z[ci][0] - mu) / r * gv.x + bv.x;
    z[ci][1] = (z[ci][1] - mu) / r * gv.y + bv.y;
    z[ci][2] = (z[ci][2] - mu) / r * gv.z + bv.z;
    z[ci][3] = (z[ci][3] - mu) / r * gv.w + bv.w;
  }
  float4 cv = ((const float4*)(c + (size_t)b * 1024))[t];
  float cvv[4] = {cv.x, cv.y, cv.z, cv.w};
  float nc[4];
#pragma unroll
  for (int i = 0; i < 4; ++i)
    nc[i] = cvv[i] * sigm(z[2][i] + 1.0f) + sigm(z[0][i]) * tanhf(z[1][i]);
  float s = nc[0] + nc[1] + nc[2] + nc[3];
  float mu = bsum<4>(s, shs) * (1.0f / 1024.0f);
  float ss = 0.f;
#pragma unroll
  for (int i = 0; i < 4; ++i) { float d = nc[i] - mu; ss += d * d; }
  float var = bsum<4>(ss, shs) * (1.0f / 1024.0f);
  float r2 = sqrtf(var + 1e-5f);
  float4 g2v = ((const float4*)g2)[t];
  float4 b2v = ((const float4*)b2)[t];
  float g2a[4] = {g2v.x, g2v.y, g2v.z, g2v.w};
  float b2a[4] = {b2v.x, b2v.y, b2v.z, b2v.w};
  float4 hv = ((const float4*)(he + (size_t)b * 1024))[t];
  float hva[4] = {hv.x, hv.y, hv.z, hv.w};
  float4 o1, o2;
  float nh[4], rr[4];
#pragma unroll
  for (int i = 0; i < 4; ++i) {
    float ncn = (nc[i] - mu) / r2 * g2a[i] + b2a[i];
    nh[i] = tanhf(ncn) * sigm(z[3][i]);
    rr[i] = tanhf(hva[i]) * sigm(z[4][i]);
  }
  o1.x = nh[0]; o1.y = nh[1]; o1.z = nh[2]; o1.w = nh[3];
  o2.x = rr[0]; o2.y = rr[1]; o2.z = rr[2]; o2.w = rr[3];
  ((float4*)(out + (size_t)b * 2048))[t] = o1;
  ((float4*)(out + (size_t)b * 2048 + 1024))[t] = o2;
}

// ---------- launch ----------
extern "C" void kernel_launch(void* const* d_in, const int* in_sizes, int n_in,
                              void* d_out, int out_size, void* d_ws, size_t ws_size,
                              hipStream_t stream) {
  const float* x = (const float*)d_in[0];
  const float* c = (const float*)d_in[1];
  const float* hmem = (const float*)d_in[2];
  const float* ut = (const float*)d_in[3];
  const float* prev = (const float*)d_in[4];
  const float* gu = (const float*)d_in[5];
  const float* keys = (const float*)d_in[6];
  const float* veca = (const float*)d_in[7];
  const float* fcw = (const float*)d_in[8];
  const float* fcb = (const float*)d_in[9];
  const float* Wf = (const float*)d_in[10];
  const float* bias = (const float*)d_in[11];
  const float* Wf1 = (const float*)d_in[12];
  const float* bias1 = (const float*)d_in[13];
  const float* ln1g = (const float*)d_in[14];
  const float* ln1b = (const float*)d_in[15];
  const float* ln2g = (const float*)d_in[16];
  const float* ln2b = (const float*)d_in[17];
  const float* ln3g = (const float*)d_in[18];
  const float* ln3b = (const float*)d_in[19];
  const float* ln4g = (const float*)d_in[20];
  const float* ln4b = (const float*)d_in[21];

  char* ws = (char*)d_ws;
  float* UN = (float*)(ws + 0);            // 128 KB
  float* A2 = (float*)(ws + 131072);       // 128 KB
  float* A1 = (float*)(ws + 262144);       // 256 KB
  u16* W3H = (u16*)(ws + 524288);          // 512 KB
  u16* W3L = (u16*)(ws + 1048576);         // 512 KB
  float* SP = (float*)(ws + 1572864);      // 512 KB
  float* HE = (float*)(ws + 2097152);      // 1 MB
  u16* AB1 = (u16*)(ws + 3145728);         // 1.25 MB
  u16* AB2 = (u16*)(ws + 4456448);         // 1.25 MB
  float* Z1p = (float*)(ws + 5767168);     // 16 MB (8 x 256x2048 f32)
  float* Z2p = (float*)(ws + 22544384);    // 20 MB (4 x 256x5120 f32) -> ends ~43.5 MB

  hipMemsetAsync(A1, 0, (size_t)256 * 256 * 4, stream);
  k_prep<<<512, 256, 0, stream>>>(fcw, keys, ut, fcb, W3H, W3L, A2, UN);
  k_a1<<<832, 256, 0, stream>>>(x, c, UN, fcw, A1);
  k2_score<<<512, 256, 0, stream>>>(hmem, W3H, W3L, A1, A2, veca, SP);
  k34<<<256, 256, 0, stream>>>(SP, prev, gu, ln4g, ln4b, hmem, x, c, HE, AB1);
  gemm_cell<<<32 * 8, 256, 0, stream>>>(AB1, Wf1, Z1p, 2048, 32, 10);
  k5b<<<256, 256, 0, stream>>>(Z1p, bias1, x, c, HE, ln3g, ln3b, AB2);
  gemm_cell<<<80 * 4, 256, 0, stream>>>(AB2, Wf, Z2p, 5120, 80, 20);
  k5d<<<256, 256, 0, stream>>>(Z2p, bias, c, HE, ln1g, ln1b, ln2g, ln2b, (float*)d_out);
}

// Round 5
// 408.731 us; speedup vs baseline: 1.4926x; 1.0435x over previous
//
#include <hip/hip_runtime.h>
#include <cstdint>
#include <cstddef>

typedef unsigned short u16;
typedef float floatx4 __attribute__((ext_vector_type(4)));
typedef __bf16 bf16x8 __attribute__((ext_vector_type(8)));
typedef unsigned short u16x8 __attribute__((ext_vector_type(8)));
typedef unsigned short u16x4 __attribute__((ext_vector_type(4)));

// ---------- helpers ----------
__device__ __forceinline__ u16 f2bf(float f) {
  unsigned u = __float_as_uint(f);
  unsigned r = u + 0x7FFFu + ((u >> 16) & 1u);   // RNE
  return (u16)(r >> 16);
}
__device__ __forceinline__ float bf2f(u16 h) {
  return __uint_as_float(((unsigned)h) << 16);
}
__device__ __forceinline__ void gl_lds16(const void* g, void* l) {
  __builtin_amdgcn_global_load_lds(
      (const __attribute__((address_space(1))) unsigned int*)g,
      (__attribute__((address_space(3))) unsigned int*)l, 16, 0, 0);
}
__device__ __forceinline__ float wsum(float v) {
#pragma unroll
  for (int m = 32; m > 0; m >>= 1) v += __shfl_xor(v, m, 64);
  return v;
}
__device__ __forceinline__ float wmaxr(float v) {
#pragma unroll
  for (int m = 32; m > 0; m >>= 1) v = fmaxf(v, __shfl_xor(v, m, 64));
  return v;
}
template <int NW>
__device__ __forceinline__ float bsum(float v, float* sh) {
  int lane = threadIdx.x & 63, wid = threadIdx.x >> 6;
  v = wsum(v);
  __syncthreads();
  if (lane == 0) sh[wid] = v;
  __syncthreads();
  float t = 0.f;
#pragma unroll
  for (int i = 0; i < NW; ++i) t += sh[i];
  return t;
}
template <int NW>
__device__ __forceinline__ float bmaxr(float v, float* sh) {
  int lane = threadIdx.x & 63, wid = threadIdx.x >> 6;
  v = wmaxr(v);
  __syncthreads();
  if (lane == 0) sh[wid] = v;
  __syncthreads();
  float t = sh[0];
#pragma unroll
  for (int i = 1; i < NW; ++i) t = fmaxf(t, sh[i]);
  return t;
}
__device__ __forceinline__ float sigm(float x) { return 1.0f / (1.0f + expf(-x)); }

// ---------- prep: W3 hi/lo FRAG-MAJOR pack, A2 = fc_b + keys@W2, u_norm ----------
// W3 pack: element [k = ks*32 + q*8 + j][col = tc*16 + r16] stored at
// ((ks*16 + tc)*64 + (q*16+r16))*8 + j  -> one wave reads 1KB contiguous per tile.
// blocks 0..127: (ks = blk>>2, qq = blk&3 -> tc = qq*4 + (t>>6))
// blocks 128..255: A2 row m; 256..511: u_norm row b
__global__ __launch_bounds__(256) void k_prep(
    const float* __restrict__ fcw, const float* __restrict__ keys,
    const float* __restrict__ ut, const float* __restrict__ fcb,
    u16* __restrict__ W3H, u16* __restrict__ W3L,
    float* __restrict__ A2, float* __restrict__ UN) {
  __shared__ float kr[64];
  __shared__ float shs[4];
  int blk = blockIdx.x, t = threadIdx.x;
  if (blk < 128) {
    int ks = blk >> 2, qq = blk & 3;
    int tc = qq * 4 + (t >> 6);
    int lane = t & 63, q = lane >> 4, r16 = lane & 15;
    u16x8 vh, vl;
#pragma unroll
    for (int j = 0; j < 8; ++j) {
      float f = fcw[(size_t)(1600 + ks * 32 + q * 8 + j) * 256 + tc * 16 + r16];
      u16 h = f2bf(f);
      vh[j] = h;
      vl[j] = f2bf(f - bf2f(h));
    }
    size_t o = (((size_t)ks * 16 + tc) * 64 + lane) * 8;
    *(u16x8*)&W3H[o] = vh;
    *(u16x8*)&W3L[o] = vl;
  } else if (blk < 256) {
    int m = blk - 128;
    if (t < 64) kr[t] = keys[m * 64 + t];
    __syncthreads();
    float acc = fcb[t];
#pragma unroll 8
    for (int j = 0; j < 64; ++j)
      acc = fmaf(kr[j], fcw[(size_t)(1536 + j) * 256 + t], acc);
    A2[m * 256 + t] = acc;
  } else {
    int b = blk - 256;
    float v = (t < 128) ? ut[b * 128 + t] : 0.f;
    float s = bsum<4>(v * v, shs);
    float dnm = fmaxf(sqrtf(s), 1e-12f);
    if (t < 128) UN[b * 128 + t] = v / dnm;
  }
}

// ---------- A1[b,k] += xc_un[b]@W1/W4 : split-K f32, atomic epilogue ----------
__global__ __launch_bounds__(256) void k_a1(
    const float* __restrict__ x, const float* __restrict__ c,
    const float* __restrict__ un, const float* __restrict__ fcw,
    float* __restrict__ A1) {
  __shared__ float sh[512];
  int kc = blockIdx.x % 26;
  int bg = blockIdx.x / 26;
  int t = threadIdx.x;
  int g0 = kc * 64;
  int row_base = (g0 < 1536) ? g0 : g0 + 1088;
#pragma unroll
  for (int p = 0; p < 2; ++p) {
    int idx = p * 256 + t;
    int bl = idx >> 6, j = idx & 63;
    int b = bg * 8 + bl;
    int g = g0 + j;
    float v;
    if (g < 512) v = x[b * 512 + g];
    else if (g < 1536) v = c[b * 1024 + (g - 512)];
    else v = un[b * 128 + (g - 1536)];
    sh[idx] = v;
  }
  __syncthreads();
  float acc[8];
#pragma unroll
  for (int i = 0; i < 8; ++i) acc[i] = 0.f;
#pragma unroll 4
  for (int j = 0; j < 64; ++j) {
    float wv = fcw[(size_t)(row_base + j) * 256 + t];
#pragma unroll
    for (int bl = 0; bl < 8; ++bl)
      acc[bl] = fmaf(sh[bl * 64 + j], wv, acc[bl]);
  }
#pragma unroll
  for (int bl = 0; bl < 8; ++bl)
    atomicAdd(&A1[(bg * 8 + bl) * 256 + t], acc[bl]);
}

// ---------- K2: score GEMM — B direct-to-registers, A-only LDS (16KB) ----------
// grid 1024 = (b, hf, ch). 256 thr = 4 waves; wave tile 64 rows x 32 cols.
// B frags register-double-buffered from frag-major W3H/W3L (no B LDS, no DMA).
// 3-pass split-bf16: hh + hl + lh.
__global__ __launch_bounds__(256, 4) void k2_score(
    const float* __restrict__ hmem, const u16* __restrict__ W3H,
    const u16* __restrict__ W3L, const float* __restrict__ A1,
    const float* __restrict__ A2, const float* __restrict__ va,
    float* __restrict__ sp) {
  __shared__ __align__(16) u16 Ah[2][2048];
  __shared__ __align__(16) u16 Al[2][2048];
  const int bi = blockIdx.x;
  const int b = bi >> 2, hf = (bi >> 1) & 1, ch = bi & 1;
  const int t = threadIdx.x;
  const int lane = t & 63, w = t >> 6;
  const int q = lane >> 4, r16 = lane & 15;
  const int slot = q ^ ((r16 >> 1) & 3);

  floatx4 acc[4][2];
#pragma unroll
  for (int i = 0; i < 4; ++i)
#pragma unroll
    for (int j = 0; j < 2; ++j) acc[i][j] = (floatx4){0.f, 0.f, 0.f, 0.f};

  // A staging: thread (m_st 0..63, qh 0..3) owns octet qh of row m_st
  const int m_st = t >> 2, qh = t & 3;
  const int wslot = qh ^ ((m_st >> 1) & 3);
  const int aw_idx = m_st * 32 + wslot * 8;
  const float* aptr = hmem + ((size_t)(b * 128 + hf * 64 + m_st)) * 1024 + qh * 8;

  int aoff[4];
#pragma unroll
  for (int i = 0; i < 4; ++i) aoff[i] = (i * 16 + r16) * 32 + slot * 8;

  // B frag pointers (frag-major layout): tile index tc = ch*8 + w*2 + ct
  const int tc0 = ch * 8 + w * 2;
  const u16* pBH = W3H + ((size_t)tc0 * 64 + lane) * 8;
  const u16* pBL = W3L + ((size_t)tc0 * 64 + lane) * 8;

  u16x8 bhC[2], blC[2], bhN[2], blN[2];
  bhC[0] = *(const u16x8*)(pBH);
  bhC[1] = *(const u16x8*)(pBH + 512);
  blC[0] = *(const u16x8*)(pBL);
  blC[1] = *(const u16x8*)(pBL + 512);

  float pv[8];
#pragma unroll
  for (int i = 0; i < 8; ++i) pv[i] = aptr[i];   // A step 0
  {
    u16x8 hh, ll;
#pragma unroll
    for (int i = 0; i < 8; ++i) {
      u16 h = f2bf(pv[i]);
      hh[i] = h;
      ll[i] = f2bf(pv[i] - bf2f(h));
    }
    *(u16x8*)&Ah[0][aw_idx] = hh;
    *(u16x8*)&Al[0][aw_idx] = ll;
  }
#pragma unroll
  for (int i = 0; i < 8; ++i) pv[i] = aptr[32 + i];  // A step 1

  auto stageA = [&](int buf) {
    u16x8 hh, ll;
#pragma unroll
    for (int i = 0; i < 8; ++i) {
      u16 h = f2bf(pv[i]);
      hh[i] = h;
      ll[i] = f2bf(pv[i] - bf2f(h));
    }
    *(u16x8*)&Ah[buf][aw_idx] = hh;
    *(u16x8*)&Al[buf][aw_idx] = ll;
  };
  auto comp = [&](int buf, u16x8* bh, u16x8* bl) {
    bf16x8 ah[4], al[4];
#pragma unroll
    for (int i = 0; i < 4; ++i) {
      ah[i] = __builtin_bit_cast(bf16x8, *(const u16x8*)&Ah[buf][aoff[i]]);
      al[i] = __builtin_bit_cast(bf16x8, *(const u16x8*)&Al[buf][aoff[i]]);
    }
#pragma unroll
    for (int ct = 0; ct < 2; ++ct) {
      bf16x8 bhv = __builtin_bit_cast(bf16x8, bh[ct]);
      bf16x8 blv = __builtin_bit_cast(bf16x8, bl[ct]);
#pragma unroll
      for (int i = 0; i < 4; ++i) {
        acc[i][ct] = __builtin_amdgcn_mfma_f32_16x16x32_bf16(ah[i], bhv, acc[i][ct], 0, 0, 0);
        acc[i][ct] = __builtin_amdgcn_mfma_f32_16x16x32_bf16(ah[i], blv, acc[i][ct], 0, 0, 0);
        acc[i][ct] = __builtin_amdgcn_mfma_f32_16x16x32_bf16(al[i], bhv, acc[i][ct], 0, 0, 0);
      }
    }
  };

#pragma unroll 2
  for (int ks = 0; ks < 32; ++ks) {
    __syncthreads();
    const int cur = ks & 1;
    if (ks < 31) {
      const size_t so = (size_t)(ks + 1) * 8192;
      if (cur == 0) {
        bhN[0] = *(const u16x8*)(pBH + so);
        bhN[1] = *(const u16x8*)(pBH + so + 512);
        blN[0] = *(const u16x8*)(pBL + so);
        blN[1] = *(const u16x8*)(pBL + so + 512);
      } else {
        bhC[0] = *(const u16x8*)(pBH + so);
        bhC[1] = *(const u16x8*)(pBH + so + 512);
        blC[0] = *(const u16x8*)(pBL + so);
        blC[1] = *(const u16x8*)(pBL + so + 512);
      }
      stageA(cur ^ 1);
      if (ks < 30) {
        const float* np = aptr + (ks + 2) * 32;
#pragma unroll
        for (int i = 0; i < 8; ++i) pv[i] = np[i];
      }
    }
    if (cur == 0) comp(0, bhC, blC);
    else comp(1, bhN, blN);
  }

  // epilogue: pre = acc + A1[b,col] + A2[m,col]; partial = sum_cols tanh(pre)*va
  float rs[4][4];
#pragma unroll
  for (int i = 0; i < 4; ++i)
#pragma unroll
    for (int r = 0; r < 4; ++r) rs[i][r] = 0.f;
#pragma unroll
  for (int ct = 0; ct < 2; ++ct) {
    int col = ch * 128 + w * 32 + ct * 16 + r16;
    float a1v = A1[b * 256 + col];
    float vav = va[col];
#pragma unroll
    for (int i = 0; i < 4; ++i) {
      int m0 = hf * 64 + i * 16 + q * 4;
#pragma unroll
      for (int r = 0; r < 4; ++r) {
        float pre = acc[i][ct][r] + a1v + A2[(m0 + r) * 256 + col];
        rs[i][r] += tanhf(pre) * vav;
      }
    }
  }
#pragma unroll
  for (int mask = 1; mask <= 8; mask <<= 1)
#pragma unroll
    for (int i = 0; i < 4; ++i)
#pragma unroll
      for (int r = 0; r < 4; ++r) rs[i][r] += __shfl_xor(rs[i][r], mask, 64);
  if (r16 == 0) {
    int part = ch * 4 + w;
#pragma unroll
    for (int i = 0; i < 4; ++i)
#pragma unroll
      for (int r = 0; r < 4; ++r) {
        int row = hf * 64 + i * 16 + q * 4 + r;
        sp[part * 32768 + b * 128 + row] = rs[i][r];
      }
  }
}

// ---------- K34: softmax/hard-read + h_entry gather + AB1 build ----------
__global__ __launch_bounds__(256) void k34(
    const float* __restrict__ sp, const float* __restrict__ prev,
    const float* __restrict__ gu, const float* __restrict__ g4,
    const float* __restrict__ b4, const float* __restrict__ hmem,
    const float* __restrict__ x, const float* __restrict__ c,
    float* __restrict__ he, u16* __restrict__ ab1) {
  __shared__ float wsw[128];
  __shared__ float shs[4];
  int b = blockIdx.x, t = threadIdx.x;
  bool act = (t < 128);
  float s = 0.f;
  if (act) {
    int bm = b * 128 + t;
#pragma unroll
    for (int p = 0; p < 8; ++p) s += sp[p * 32768 + bm];
    s -= prev[bm] * 100.0f;
  }
  float mu = bsum<4>(s, shs) * (1.0f / 128.0f);
  float d = act ? (s - mu) : 0.f;
  float var = bsum<4>(d * d, shs) * (1.0f / 128.0f);
  float z = -INFINITY;
  if (act) {
    float sn = d / sqrtf(var + 1e-5f) * g4[t] + b4[t];
    float gv = -logf(1e-20f - logf(1e-20f + gu[b * 128 + t]));
    z = sn + gv;   // TAU = 1
  }
  float zm = bmaxr<4>(z, shs);
  float e = act ? expf(z - zm) : 0.f;
  float Zs = bsum<4>(e, shs);
  float y = e / Zs;
  float ym = bmaxr<4>(y, shs);
  if (act) {
    float hard = (y == ym) ? 1.0f : 0.0f;
    wsw[t] = (hard - y) + y;   // exactly 0 for non-selected rows
  }
  __syncthreads();
  float4 a;
  a.x = a.y = a.z = a.w = 0.f;
  for (int mm = 0; mm < 128; ++mm) {
    float wm = wsw[mm];
    if (wm != 0.0f) {
      float4 v = ((const float4*)(hmem + ((size_t)(b * 128 + mm)) * 1024))[t];
      a.x = fmaf(wm, v.x, a.x);
      a.y = fmaf(wm, v.y, a.y);
      a.z = fmaf(wm, v.z, a.z);
      a.w = fmaf(wm, v.w, a.w);
    }
  }
  ((float4*)(he + (size_t)b * 1024))[t] = a;
  const int sx = ((b >> 1) & 3) << 3;
  u16* row = ab1 + (size_t)b * 2560;
  if (t < 128) {
    float4 xv = ((const float4*)(x + (size_t)b * 512))[t];
    u16x4 o = {f2bf(xv.x), f2bf(xv.y), f2bf(xv.z), f2bf(xv.w)};
    *(u16x4*)&row[(t * 4) ^ sx] = o;
  }
  {
    float4 cv = ((const float4*)(c + (size_t)b * 1024))[t];
    u16x4 o = {f2bf(cv.x), f2bf(cv.y), f2bf(cv.z), f2bf(cv.w)};
    *(u16x4*)&row[(512 + t * 4) ^ sx] = o;
  }
  {
    u16x4 o = {f2bf(a.x), f2bf(a.y), f2bf(a.z), f2bf(a.w)};
    *(u16x4*)&row[(1536 + t * 4) ^ sx] = o;
  }
}

// ---------- cell GEMM: 256x32 col-split tiles, Zp[kc] partial stores ----------
__global__ __launch_bounds__(256) void gemm_cell(
    const u16* __restrict__ Abf, const float* __restrict__ W,
    float* __restrict__ Zp, int N, int nblk, int nsteps) {
  __shared__ __align__(16) u16 Asm[256 * 32];
  __shared__ __align__(16) float Bf[32 * 32];
  __shared__ __align__(16) u16 Bsm[32 * 40];
  int cb = blockIdx.x % nblk;
  int kc = blockIdx.x / nblk;
  int t = threadIdx.x, lane = t & 63, w = t >> 6;
  int q = lane >> 4, r16 = lane & 15;
  const int axor = ((r16 >> 1) & 3) << 3;
  floatx4 acc[4][2];
#pragma unroll
  for (int i = 0; i < 4; ++i)
#pragma unroll
    for (int j = 0; j < 2; ++j) acc[i][j] = (floatx4){0.f, 0.f, 0.f, 0.f};
  int k0 = kc * nsteps * 32;
  for (int ks = 0; ks < nsteps; ++ks) {
    int k = k0 + ks * 32;
    // A: 256x32 bf16 = 16KB DMA
#pragma unroll
    for (int i = 0; i < 4; ++i) {
      int L = (w * 4 + i) * 1024 + lane * 16;
      int row = L >> 6, off = L & 63;
      gl_lds16((const char*)Abf + (size_t)row * 5120 + k * 2 + off, (char*)Asm + L);
    }
    // B: 32k x 32col f32 = 4KB DMA
    {
      int L = t * 16;
      int kr = L >> 7, off = L & 127;
      gl_lds16((const char*)W + ((size_t)(k + kr) * N + cb * 32) * 4 + off, (char*)Bf + L);
    }
    __syncthreads();
    // transpose-convert B -> [col][k] bf16 (stride 40)
    {
      int cc = t & 31, p = t >> 5;
      u16x4 hh;
#pragma unroll
      for (int i2 = 0; i2 < 4; ++i2) hh[i2] = f2bf(Bf[(p * 4 + i2) * 32 + cc]);
      *(u16x4*)&Bsm[cc * 40 + p * 4] = hh;
    }
    __syncthreads();
    bf16x8 af[4];
#pragma unroll
    for (int i = 0; i < 4; ++i) {
      int row = w * 64 + i * 16 + r16;
      af[i] = __builtin_bit_cast(bf16x8, *(const u16x8*)&Asm[(row * 32 + q * 8) ^ axor]);
    }
#pragma unroll
    for (int ct = 0; ct < 2; ++ct) {
      int col = ct * 16 + r16;
      bf16x8 bb = __builtin_bit_cast(bf16x8, *(const u16x8*)&Bsm[col * 40 + q * 8]);
#pragma unroll
      for (int i = 0; i < 4; ++i)
        acc[i][ct] = __builtin_amdgcn_mfma_f32_16x16x32_bf16(af[i], bb, acc[i][ct], 0, 0, 0);
    }
    __syncthreads();
  }
  float* dst = Zp + (size_t)kc * 256 * N;
#pragma unroll
  for (int ct = 0; ct < 2; ++ct)
#pragma unroll
    for (int i = 0; i < 4; ++i)
#pragma unroll
      for (int r = 0; r < 4; ++r) {
        int col = cb * 32 + ct * 16 + r16;
        int row = w * 64 + i * 16 + q * 4 + r;
        dst[(size_t)row * N + col] = acc[i][ct][r];
      }
}

// ---------- K5b: sum Z1 partials, LN3+sigmoid gate, build gated AB2 ----------
__global__ __launch_bounds__(256) void k5b(
    const float* __restrict__ Z1p, const float* __restrict__ bias1,
    const float* __restrict__ x, const float* __restrict__ c,
    const float* __restrict__ he, const float* __restrict__ g3,
    const float* __restrict__ b3, u16* __restrict__ ab2) {
  __shared__ float shs[4];
  int b = blockIdx.x, t = threadIdx.x;
  const float4* bp = (const float4*)bias1;
  float4 q0 = bp[t], q1 = bp[256 + t];
  float za[4] = {q0.x, q0.y, q0.z, q0.w};
  float zb[4] = {q1.x, q1.y, q1.z, q1.w};
#pragma unroll
  for (int kc = 0; kc < 8; ++kc) {
    const float4* zp = (const float4*)(Z1p + (size_t)kc * 524288 + (size_t)b * 2048);
    float4 v0 = zp[t], v1 = zp[256 + t];
    za[0] += v0.x; za[1] += v0.y; za[2] += v0.z; za[3] += v0.w;
    zb[0] += v1.x; zb[1] += v1.y; zb[2] += v1.z; zb[3] += v1.w;
  }
  float g1a[4], g1b[4];
  {
    float s = za[0] + za[1] + za[2] + za[3];
    float mu = bsum<4>(s, shs) * (1.0f / 1024.0f);
    float ss = 0.f;
#pragma unroll
    for (int i = 0; i < 4; ++i) { float d = za[i] - mu; ss += d * d; }
    float var = bsum<4>(ss, shs) * (1.0f / 1024.0f);
    float r = sqrtf(var + 1e-5f);
    float4 gv = ((const float4*)g3)[t];
    float4 bv = ((const float4*)b3)[t];
    g1a[0] = sigm((za[0] - mu) / r * gv.x + bv.x);
    g1a[1] = sigm((za[1] - mu) / r * gv.y + bv.y);
    g1a[2] = sigm((za[2] - mu) / r * gv.z + bv.z);
    g1a[3] = sigm((za[3] - mu) / r * gv.w + bv.w);
  }
  {
    float s = zb[0] + zb[1] + zb[2] + zb[3];
    float mu = bsum<4>(s, shs) * (1.0f / 1024.0f);
    float ss = 0.f;
#pragma unroll
    for (int i = 0; i < 4; ++i) { float d = zb[i] - mu; ss += d * d; }
    float var = bsum<4>(ss, shs) * (1.0f / 1024.0f);
    float r = sqrtf(var + 1e-5f);
    float4 gv = ((const float4*)g3)[256 + t];
    float4 bv = ((const float4*)b3)[256 + t];
    g1b[0] = sigm((zb[0] - mu) / r * gv.x + bv.x);
    g1b[1] = sigm((zb[1] - mu) / r * gv.y + bv.y);
    g1b[2] = sigm((zb[2] - mu) / r * gv.z + bv.z);
    g1b[3] = sigm((zb[3] - mu) / r * gv.w + bv.w);
  }
  const int sx = ((b >> 1) & 3) << 3;
  u16* row = ab2 + (size_t)b * 2560;
  if (t < 128) {
    float4 xv = ((const float4*)(x + (size_t)b * 512))[t];
    u16x4 o = {f2bf(xv.x), f2bf(xv.y), f2bf(xv.z), f2bf(xv.w)};
    *(u16x4*)&row[(t * 4) ^ sx] = o;
  }
  {
    float4 cv = ((const float4*)(c + (size_t)b * 1024))[t];
    u16x4 o = {f2bf(cv.x * g1a[0]), f2bf(cv.y * g1a[1]), f2bf(cv.z * g1a[2]), f2bf(cv.w * g1a[3])};
    *(u16x4*)&row[(512 + t * 4) ^ sx] = o;
  }
  {
    float4 hv = ((const float4*)(he + (size_t)b * 1024))[t];
    u16x4 o = {f2bf(hv.x * g1b[0]), f2bf(hv.y * g1b[1]), f2bf(hv.z * g1b[2]), f2bf(hv.w * g1b[3])};
    *(u16x4*)&row[(1536 + t * 4) ^ sx] = o;
  }
}

// ---------- K5d: sum Z2 partials, LN1(5), cell update, LN2, outputs ----------
__global__ __launch_bounds__(256) void k5d(
    const float* __restrict__ Z2p, const float* __restrict__ bias,
    const float* __restrict__ c, const float* __restrict__ he,
    const float* __restrict__ g1, const float* __restrict__ b1,
    const float* __restrict__ g2, const float* __restrict__ b2,
    float* __restrict__ out) {
  __shared__ float shs[4];
  int b = blockIdx.x, t = threadIdx.x;
  const float4* bp = (const float4*)bias;
  float z[5][4];
#pragma unroll
  for (int ci = 0; ci < 5; ++ci) {
    float4 bb = bp[ci * 256 + t];
    z[ci][0] = bb.x; z[ci][1] = bb.y; z[ci][2] = bb.z; z[ci][3] = bb.w;
  }
#pragma unroll
  for (int kc = 0; kc < 4; ++kc) {
    const float4* zp = (const float4*)(Z2p + (size_t)kc * 1310720 + (size_t)b * 5120);
#pragma unroll
    for (int ci = 0; ci < 5; ++ci) {
      float4 v = zp[ci * 256 + t];
      z[ci][0] += v.x; z[ci][1] += v.y; z[ci][2] += v.z; z[ci][3] += v.w;
    }
  }
#pragma unroll
  for (int ci = 0; ci < 5; ++ci) {
    float s = z[ci][0] + z[ci][1] + z[ci][2] + z[ci][3];
    float mu = bsum<4>(s, shs) * (1.0f / 1024.0f);
    float ss = 0.f;
#pragma unroll
    for (int i = 0; i < 4; ++i) { float d = z[ci][i] - mu; ss += d * d; }
    float var = bsum<4>(ss, shs) * (1.0f / 1024.0f);
    float r = sqrtf(var + 1e-5f);
    float4 gv = ((const float4*)g1)[ci * 256 + t];
    float4 bv = ((const float4*)b1)[ci * 256 + t];
    z[ci][0] = (z[ci][0] - mu) / r * gv.x + bv.x;
    z[ci][1] = (z[ci][1] - mu) / r * gv.y + bv.y;
    z[ci][2] = (z[ci][2] - mu) / r * gv.z + bv.z;
    z[ci][3] = (z[ci][3] - mu) / r * gv.w + bv.w;
  }
  float4 cv = ((const float4*)(c + (size_t)b * 1024))[t];
  float cvv[4] = {cv.x, cv.y, cv.z, cv.w};
  float nc[4];
#pragma unroll
  for (int i = 0; i < 4; ++i)
    nc[i] = cvv[i] * sigm(z[2][i] + 1.0f) + sigm(z[0][i]) * tanhf(z[1][i]);
  float s = nc[0] + nc[1] + nc[2] + nc[3];
  float mu = bsum<4>(s, shs) * (1.0f / 1024.0f);
  float ss = 0.f;
#pragma unroll
  for (int i = 0; i < 4; ++i) { float d = nc[i] - mu; ss += d * d; }
  float var = bsum<4>(ss, shs) * (1.0f / 1024.0f);
  float r2 = sqrtf(var + 1e-5f);
  float4 g2v = ((const float4*)g2)[t];
  float4 b2v = ((const float4*)b2)[t];
  float g2a[4] = {g2v.x, g2v.y, g2v.z, g2v.w};
  float b2a[4] = {b2v.x, b2v.y, b2v.z, b2v.w};
  float4 hv = ((const float4*)(he + (size_t)b * 1024))[t];
  float hva[4] = {hv.x, hv.y, hv.z, hv.w};
  float4 o1, o2;
  float nh[4], rr[4];
#pragma unroll
  for (int i = 0; i < 4; ++i) {
    float ncn = (nc[i] - mu) / r2 * g2a[i] + b2a[i];
    nh[i] = tanhf(ncn) * sigm(z[3][i]);
    rr[i] = tanhf(hva[i]) * sigm(z[4][i]);
  }
  o1.x = nh[0]; o1.y = nh[1]; o1.z = nh[2]; o1.w = nh[3];
  o2.x = rr[0]; o2.y = rr[1]; o2.z = rr[2]; o2.w = rr[3];
  ((float4*)(out + (size_t)b * 2048))[t] = o1;
  ((float4*)(out + (size_t)b * 2048 + 1024))[t] = o2;
}

// ---------- launch ----------
extern "C" void kernel_launch(void* const* d_in, const int* in_sizes, int n_in,
                              void* d_out, int out_size, void* d_ws, size_t ws_size,
                              hipStream_t stream) {
  const float* x = (const float*)d_in[0];
  const float* c = (const float*)d_in[1];
  const float* hmem = (const float*)d_in[2];
  const float* ut = (const float*)d_in[3];
  const float* prev = (const float*)d_in[4];
  const float* gu = (const float*)d_in[5];
  const float* keys = (const float*)d_in[6];
  const float* veca = (const float*)d_in[7];
  const float* fcw = (const float*)d_in[8];
  const float* fcb = (const float*)d_in[9];
  const float* Wf = (const float*)d_in[10];
  const float* bias = (const float*)d_in[11];
  const float* Wf1 = (const float*)d_in[12];
  const float* bias1 = (const float*)d_in[13];
  const float* ln1g = (const float*)d_in[14];
  const float* ln1b = (const float*)d_in[15];
  const float* ln2g = (const float*)d_in[16];
  const float* ln2b = (const float*)d_in[17];
  const float* ln3g = (const float*)d_in[18];
  const float* ln3b = (const float*)d_in[19];
  const float* ln4g = (const float*)d_in[20];
  const float* ln4b = (const float*)d_in[21];

  char* ws = (char*)d_ws;
  float* UN = (float*)(ws + 0);            // 128 KB
  float* A2 = (float*)(ws + 131072);       // 128 KB
  float* A1 = (float*)(ws + 262144);       // 256 KB
  u16* W3H = (u16*)(ws + 524288);          // 512 KB
  u16* W3L = (u16*)(ws + 1048576);         // 512 KB
  float* SP = (float*)(ws + 1572864);      // 1 MB (8 partials)
  float* HE = (float*)(ws + 2621440);      // 1 MB
  u16* AB1 = (u16*)(ws + 3670016);         // 1.25 MB
  u16* AB2 = (u16*)(ws + 4980736);         // 1.25 MB
  float* Z1p = (float*)(ws + 6291456);     // 16 MB (8 x 256x2048 f32)
  float* Z2p = (float*)(ws + 23068672);    // 20 MB (4 x 256x5120 f32) -> ends ~42 MB

  hipMemsetAsync(A1, 0, (size_t)256 * 256 * 4, stream);
  k_prep<<<512, 256, 0, stream>>>(fcw, keys, ut, fcb, W3H, W3L, A2, UN);
  k_a1<<<832, 256, 0, stream>>>(x, c, UN, fcw, A1);
  k2_score<<<1024, 256, 0, stream>>>(hmem, W3H, W3L, A1, A2, veca, SP);
  k34<<<256, 256, 0, stream>>>(SP, prev, gu, ln4g, ln4b, hmem, x, c, HE, AB1);
  gemm_cell<<<64 * 8, 256, 0, stream>>>(AB1, Wf1, Z1p, 2048, 64, 10);
  k5b<<<256, 256, 0, stream>>>(Z1p, bias1, x, c, HE, ln3g, ln3b, AB2);
  gemm_cell<<<160 * 4, 256, 0, stream>>>(AB2, Wf, Z2p, 5120, 160, 20);
  k5d<<<256, 256, 0, stream>>>(Z2p, bias, c, HE, ln1g, ln1b, ln2g, ln2b, (float*)d_out);
}